// Round 2
// baseline (1289.990 us; speedup 1.0000x reference)
//
#include <hip/hip_runtime.h>
#include <math.h>

#define NN 100000
#define NE 1600000
#define NEG_SLOPE 0.2f

__device__ __forceinline__ float b2f(unsigned short u) {
  union { unsigned u; float f; } c; c.u = ((unsigned)u) << 16; return c.f;
}
__device__ __forceinline__ unsigned short f2b(float x) {
  union { float f; unsigned u; } c; c.f = x;
  unsigned r = c.u + 0x7FFFu + ((c.u >> 16) & 1u);
  return (unsigned short)(r >> 16);
}
__device__ __forceinline__ float wred(float v) {
#pragma unroll
  for (int off = 32; off > 0; off >>= 1) v += __shfl_xor(v, off, 64);
  return v;
}
__device__ __forceinline__ void fma4(float4& acc, float s, const float4& b) {
  acc.x = fmaf(s, b.x, acc.x);
  acc.y = fmaf(s, b.y, acc.y);
  acc.z = fmaf(s, b.z, acc.z);
  acc.w = fmaf(s, b.w, acc.w);
}

// ---------------- utility: zero a word range ----------------
__global__ __launch_bounds__(256) void k_zero(int* __restrict__ p, int nwords) {
  int i = blockIdx.x * 256 + threadIdx.x;
  if (i < nwords) p[i] = 0;
}

// ---------------- CSR build (unordered within row: softmax/sum are order-free) ----------------
__global__ __launch_bounds__(256) void k_deg(const int* __restrict__ dst, int* __restrict__ deg) {
  int i = blockIdx.x * 256 + threadIdx.x;
  if (i < NE) atomicAdd(&deg[dst[i]], 1);
}

__global__ __launch_bounds__(256) void k_alloc(const int* __restrict__ deg, int* __restrict__ row_start,
                                               int* __restrict__ counter, float* __restrict__ nrm) {
  int i = blockIdx.x * 256 + threadIdx.x;
  if (i < NN) {
    row_start[i] = atomicAdd(counter, deg[i]);
    nrm[i] = rsqrtf(fmaxf((float)deg[i], 1.0f));
  }
}

__global__ __launch_bounds__(256) void k_scatter(const int* __restrict__ src, const int* __restrict__ dst,
                                                 const int* __restrict__ row_start, int* __restrict__ cursor,
                                                 int* __restrict__ csr_src) {
  int i = blockIdx.x * 256 + threadIdx.x;
  if (i < NE) {
    int n = dst[i];
    int p = atomicAdd(&cursor[n], 1);
    csr_src[row_start[n] + p] = src[i];
  }
}

// ---------------- GEMM: C_bf16[N x 256] = A[N x 128] * B[128 x 256] ----------------
__global__ __launch_bounds__(256) void k_gemm_nn_bf16(const float* __restrict__ A, const float* __restrict__ B,
                                                      unsigned short* __restrict__ C) {
  __shared__ float Bl[128][68];
  int colBase = blockIdx.y * 64;
  for (int idx = threadIdx.x; idx < 128 * 64; idx += 256) {
    int k = idx >> 6, c = idx & 63;
    Bl[k][c] = B[k * 256 + colBase + c];
  }
  __syncthreads();
  int tx = threadIdx.x & 15, ty = threadIdx.x >> 4;
  int row0 = blockIdx.x * 64 + ty * 4;
  const float* ap[4];
#pragma unroll
  for (int r = 0; r < 4; ++r) ap[r] = A + (size_t)min(row0 + r, NN - 1) * 128;
  float4 acc[4];
#pragma unroll
  for (int r = 0; r < 4; ++r) acc[r] = make_float4(0.f, 0.f, 0.f, 0.f);
#pragma unroll 2
  for (int k0 = 0; k0 < 128; k0 += 4) {
    float4 b0 = *(const float4*)&Bl[k0][tx * 4];
    float4 b1 = *(const float4*)&Bl[k0 + 1][tx * 4];
    float4 b2 = *(const float4*)&Bl[k0 + 2][tx * 4];
    float4 b3 = *(const float4*)&Bl[k0 + 3][tx * 4];
#pragma unroll
    for (int r = 0; r < 4; ++r) {
      float4 a = *(const float4*)(ap[r] + k0);
      fma4(acc[r], a.x, b0); fma4(acc[r], a.y, b1);
      fma4(acc[r], a.z, b2); fma4(acc[r], a.w, b3);
    }
  }
#pragma unroll
  for (int r = 0; r < 4; ++r) {
    int row = row0 + r;
    if (row < NN) {
      ushort4 o;
      o.x = f2b(acc[r].x); o.y = f2b(acc[r].y); o.z = f2b(acc[r].z); o.w = f2b(acc[r].w);
      *(ushort4*)&C[(size_t)row * 256 + colBase + tx * 4] = o;
    }
  }
}

// ---------------- res2_f32[N x 64] = relu(A[N x 128] * W_res^T + b_res) ----------------
__global__ __launch_bounds__(256) void k_gemm_nt_bias_relu(const float* __restrict__ A, const float* __restrict__ B,
                                                           const float* __restrict__ bias, float* __restrict__ C) {
  __shared__ float Bl[128][68];
  for (int idx = threadIdx.x; idx < 64 * 128; idx += 256) {
    int d = idx >> 7, k = idx & 127;
    Bl[k][d] = B[d * 128 + k];
  }
  __syncthreads();
  int tx = threadIdx.x & 15, ty = threadIdx.x >> 4;
  int row0 = blockIdx.x * 64 + ty * 4;
  const float* ap[4];
#pragma unroll
  for (int r = 0; r < 4; ++r) ap[r] = A + (size_t)min(row0 + r, NN - 1) * 128;
  float4 acc[4];
#pragma unroll
  for (int r = 0; r < 4; ++r) acc[r] = make_float4(0.f, 0.f, 0.f, 0.f);
#pragma unroll 2
  for (int k0 = 0; k0 < 128; k0 += 4) {
    float4 b0 = *(const float4*)&Bl[k0][tx * 4];
    float4 b1 = *(const float4*)&Bl[k0 + 1][tx * 4];
    float4 b2 = *(const float4*)&Bl[k0 + 2][tx * 4];
    float4 b3 = *(const float4*)&Bl[k0 + 3][tx * 4];
#pragma unroll
    for (int r = 0; r < 4; ++r) {
      float4 a = *(const float4*)(ap[r] + k0);
      fma4(acc[r], a.x, b0); fma4(acc[r], a.y, b1);
      fma4(acc[r], a.z, b2); fma4(acc[r], a.w, b3);
    }
  }
  float4 bv = *(const float4*)&bias[tx * 4];
#pragma unroll
  for (int r = 0; r < 4; ++r) {
    int row = row0 + r;
    if (row < NN) {
      float4 v;
      v.x = fmaxf(acc[r].x + bv.x, 0.f);
      v.y = fmaxf(acc[r].y + bv.y, 0.f);
      v.z = fmaxf(acc[r].z + bv.z, 0.f);
      v.w = fmaxf(acc[r].w + bv.w, 0.f);
      *(float4*)&C[(size_t)row * 64 + tx * 4] = v;
    }
  }
}

// ---------------- attention scalars el/er: one wave per node ----------------
__global__ __launch_bounds__(256) void k_elr(const unsigned short* __restrict__ feat, const float* __restrict__ al,
                                             const float* __restrict__ ar, float* __restrict__ el,
                                             float* __restrict__ er) {
  int n = blockIdx.x * 4 + (threadIdx.x >> 6);
  int lane = threadIdx.x & 63;
  if (n >= NN) return;
  const unsigned short* f = feat + (size_t)n * 256;
  float v;
  v = b2f(f[lane]);       float l0 = wred(v * al[lane]);       float r0 = wred(v * ar[lane]);
  v = b2f(f[64 + lane]);  float l1 = wred(v * al[64 + lane]);  float r1 = wred(v * ar[64 + lane]);
  v = b2f(f[128 + lane]); float l2 = wred(v * al[128 + lane]); float r2 = wred(v * ar[128 + lane]);
  v = b2f(f[192 + lane]); float l3 = wred(v * al[192 + lane]); float r3 = wred(v * ar[192 + lane]);
  if (lane == 0) {
    *(float4*)&el[n * 4] = make_float4(l0, l1, l2, l3);
    *(float4*)&er[n * 4] = make_float4(r0, r1, r2, r3);
  }
}

// ---------------- fused edge-softmax + aggregation + relu + head-mix conv ----------------
// One wave per dst node. Lanes load 64 edges coalescedly, compute exp lane-parallel,
// then broadcast (src, a0..a3) per edge via shuffle into d-parallel accumulation.
// Softmax normalization folded in after the (linear) accumulation.
__global__ __launch_bounds__(256) void k_gat(const int* __restrict__ row_start, const int* __restrict__ deg,
                                             const int* __restrict__ csr_src, const float* __restrict__ el,
                                             const float* __restrict__ er, const unsigned short* __restrict__ feat,
                                             const unsigned short* __restrict__ resval,
                                             const float* __restrict__ gat_bias, const float* __restrict__ conv_w,
                                             const float* __restrict__ conv_b, float* __restrict__ h0,
                                             unsigned short* __restrict__ hcur) {
  int n = blockIdx.x * 4 + (threadIdx.x >> 6);
  int lane = threadIdx.x & 63;
  if (n >= NN) return;
  int s0 = row_start[n], cnt = deg[n];
  float4 er4 = *(const float4*)&er[n * 4];
  float acc0 = 0.f, acc1 = 0.f, acc2 = 0.f, acc3 = 0.f;
  float den0 = 0.f, den1 = 0.f, den2 = 0.f, den3 = 0.f;
  for (int base = 0; base < cnt; base += 64) {
    int j = base + lane;
    int s = 0;
    float x0 = 0.f, x1 = 0.f, x2 = 0.f, x3 = 0.f;
    if (j < cnt) {
      s = csr_src[s0 + j];
      float4 el4 = *(const float4*)&el[s * 4];
      float e0 = el4.x + er4.x; e0 = (e0 > 0.f) ? e0 : NEG_SLOPE * e0;
      float e1 = el4.y + er4.y; e1 = (e1 > 0.f) ? e1 : NEG_SLOPE * e1;
      float e2 = el4.z + er4.z; e2 = (e2 > 0.f) ? e2 : NEG_SLOPE * e2;
      float e3 = el4.w + er4.w; e3 = (e3 > 0.f) ? e3 : NEG_SLOPE * e3;
      x0 = __expf(e0); x1 = __expf(e1); x2 = __expf(e2); x3 = __expf(e3);
      den0 += x0; den1 += x1; den2 += x2; den3 += x3;
    }
    int m = cnt - base; if (m > 64) m = 64;
    for (int t = 0; t < m; ++t) {
      int ss = __shfl(s, t, 64);
      float a0 = __shfl(x0, t, 64);
      float a1 = __shfl(x1, t, 64);
      float a2 = __shfl(x2, t, 64);
      float a3 = __shfl(x3, t, 64);
      const unsigned short* fp = feat + (size_t)ss * 256;
      acc0 = fmaf(a0, b2f(fp[lane]), acc0);
      acc1 = fmaf(a1, b2f(fp[64 + lane]), acc1);
      acc2 = fmaf(a2, b2f(fp[128 + lane]), acc2);
      acc3 = fmaf(a3, b2f(fp[192 + lane]), acc3);
    }
  }
  den0 = wred(den0); den1 = wred(den1); den2 = wred(den2); den3 = wred(den3);
  float i0 = 1.f / fmaxf(den0, 1e-9f);
  float i1 = 1.f / fmaxf(den1, 1e-9f);
  float i2 = 1.f / fmaxf(den2, 1e-9f);
  float i3 = 1.f / fmaxf(den3, 1e-9f);
  const unsigned short* rv = resval + (size_t)n * 256;
  float hmix = conv_b[0];
  float t0;
  t0 = fmaf(acc0, i0, b2f(rv[lane]) + gat_bias[lane]);             t0 = fmaxf(t0, 0.f); hmix = fmaf(conv_w[0], t0, hmix);
  t0 = fmaf(acc1, i1, b2f(rv[64 + lane]) + gat_bias[64 + lane]);   t0 = fmaxf(t0, 0.f); hmix = fmaf(conv_w[1], t0, hmix);
  t0 = fmaf(acc2, i2, b2f(rv[128 + lane]) + gat_bias[128 + lane]); t0 = fmaxf(t0, 0.f); hmix = fmaf(conv_w[2], t0, hmix);
  t0 = fmaf(acc3, i3, b2f(rv[192 + lane]) + gat_bias[192 + lane]); t0 = fmaxf(t0, 0.f); hmix = fmaf(conv_w[3], t0, hmix);
  size_t o = (size_t)n * 64 + lane;
  h0[o] = hmix;
  hcur[o] = f2b(hmix);
}

// ---------------- APPNP step: hout = bf16(0.5*nrm[n]*sum_src(nrm[s]*hin[s]) + 0.5*h0) ----------------
__global__ __launch_bounds__(256) void k_gather(const int* __restrict__ row_start, const int* __restrict__ deg,
                                                const int* __restrict__ csr_src,
                                                const unsigned short* __restrict__ hin,
                                                const float* __restrict__ nrm, const float* __restrict__ h0,
                                                unsigned short* __restrict__ hout) {
  int n = blockIdx.x * 4 + (threadIdx.x >> 6);
  int lane = threadIdx.x & 63;
  if (n >= NN) return;
  int s0 = row_start[n], cnt = deg[n];
  float acc = 0.f;
  for (int base = 0; base < cnt; base += 64) {
    int j = base + lane;
    int s = 0; float w = 0.f;
    if (j < cnt) { s = csr_src[s0 + j]; w = nrm[s]; }
    int m = cnt - base; if (m > 64) m = 64;
    for (int t = 0; t < m; ++t) {
      int ss = __shfl(s, t, 64);
      float ww = __shfl(w, t, 64);
      acc = fmaf(ww, b2f(hin[(size_t)ss * 64 + lane]), acc);
    }
  }
  size_t o = (size_t)n * 64 + lane;
  float v = fmaf(0.5f * nrm[n], acc, 0.5f * h0[o]);
  hout[o] = f2b(v);
}

// ---------------- final residual add + BN partial sums ----------------
__global__ __launch_bounds__(256) void k_finred(const unsigned short* __restrict__ hl,
                                                const float* __restrict__ res2, float* __restrict__ hfin,
                                                float* __restrict__ bn) {
  __shared__ float s1[256], s2[256];
  int d = threadIdx.x & 63;
  int rb = blockIdx.x * 64;
  float sum = 0.f, sq = 0.f;
  for (int r = threadIdx.x >> 6; r < 64; r += 4) {
    int n = rb + r;
    if (n < NN) {
      size_t idx = (size_t)n * 64 + d;
      float v = b2f(hl[idx]) + res2[idx];
      hfin[idx] = v;
      sum += v; sq += v * v;
    }
  }
  s1[threadIdx.x] = sum; s2[threadIdx.x] = sq;
  __syncthreads();
  if (threadIdx.x < 128) { s1[threadIdx.x] += s1[threadIdx.x + 128]; s2[threadIdx.x] += s2[threadIdx.x + 128]; }
  __syncthreads();
  if (threadIdx.x < 64) {
    atomicAdd(&bn[d], s1[threadIdx.x] + s1[threadIdx.x + 64]);
    atomicAdd(&bn[64 + d], s2[threadIdx.x] + s2[threadIdx.x + 64]);
  }
}

__global__ void k_bnstats(const float* __restrict__ bn, const float* __restrict__ gamma,
                          const float* __restrict__ beta, float* __restrict__ bns) {
  int d = threadIdx.x;
  float mu = bn[d] * (1.0f / NN);
  float var = fmaxf(bn[64 + d] * (1.0f / NN) - mu * mu, 0.f);
  float sc = rsqrtf(var + 1e-5f) * gamma[d];
  bns[d] = sc;
  bns[64 + d] = beta[d] - mu * sc;
}

__global__ __launch_bounds__(256) void k_bnapply(const float* __restrict__ h, const float* __restrict__ bns,
                                                 float* __restrict__ out) {
  int i = blockIdx.x * 256 + threadIdx.x;
  if (i < NN * 64) {
    int d = i & 63;
    out[i] = fmaf(h[i], bns[d], bns[64 + d]);
  }
}

extern "C" void kernel_launch(void* const* d_in, const int* in_sizes, int n_in,
                              void* d_out, int out_size, void* d_ws, size_t ws_size,
                              hipStream_t stream) {
  const float* node_feats = (const float*)d_in[0];
  const int* src = (const int*)d_in[1];
  const int* dst = (const int*)d_in[2];
  const float* W_fc = (const float*)d_in[3];
  const float* attn_l = (const float*)d_in[4];
  const float* attn_r = (const float*)d_in[5];
  const float* W_res_gat = (const float*)d_in[6];
  const float* gat_bias = (const float*)d_in[7];
  const float* conv_w = (const float*)d_in[8];
  const float* conv_b = (const float*)d_in[9];
  const float* W_res = (const float*)d_in[10];
  const float* b_res = (const float*)d_in[11];
  const float* gamma = (const float*)d_in[12];
  const float* beta = (const float*)d_in[13];
  float* out = (float*)d_out;

  char* base = (char*)d_ws;
  size_t off = 0;
  auto alloc = [&](size_t bytes) -> char* {
    char* p = base + off;
    off = (off + bytes + 255) & ~(size_t)255;
    return p;
  };
  unsigned short* feat   = (unsigned short*)alloc((size_t)NN * 256 * 2);  // 51.2 MB
  unsigned short* resval = (unsigned short*)alloc((size_t)NN * 256 * 2);  // 51.2 MB; res2(f32,25.6MB) aliases this after k_gat
  float* res2            = (float*)resval;
  float* el              = (float*)alloc((size_t)NN * 4 * 4);
  float* er              = (float*)alloc((size_t)NN * 4 * 4);
  float* h0              = (float*)alloc((size_t)NN * 64 * 4);            // 25.6 MB; reused as hfin at the end
  unsigned short* hcur   = (unsigned short*)alloc((size_t)NN * 64 * 2);   // 12.8 MB
  unsigned short* hnxt   = (unsigned short*)alloc((size_t)NN * 64 * 2);   // 12.8 MB
  int* csr_src           = (int*)alloc((size_t)NE * 4);                   // 6.4 MB
  float* nrm             = (float*)alloc((size_t)NN * 4);
  int* row_start         = (int*)alloc((size_t)NN * 4);
  size_t zoff = off;
  int* deg               = (int*)alloc((size_t)NN * 4);
  int* cursor            = (int*)alloc((size_t)NN * 4);
  int* counter           = (int*)alloc(256);
  float* bn              = (float*)alloc(256 * 4);  // [0:64) sum, [64:128) sumsq, [128:256) scale/shift
  // total ~165 MB

  int zwords = (int)((off - zoff) / 4);
  int gE = (NE + 255) / 256;
  int gN = (NN + 255) / 256;
  int gW = (NN + 3) / 4;
  int gM = (NN + 63) / 64;
  int gV = (NN * 64 + 255) / 256;

  k_zero<<<(zwords + 255) / 256, 256, 0, stream>>>((int*)(base + zoff), zwords);
  k_deg<<<gE, 256, 0, stream>>>(dst, deg);
  k_alloc<<<gN, 256, 0, stream>>>(deg, row_start, counter, nrm);
  k_scatter<<<gE, 256, 0, stream>>>(src, dst, row_start, cursor, csr_src);

  k_gemm_nn_bf16<<<dim3(gM, 4), 256, 0, stream>>>(node_feats, W_fc, feat);
  k_gemm_nn_bf16<<<dim3(gM, 4), 256, 0, stream>>>(node_feats, W_res_gat, resval);

  k_elr<<<gW, 256, 0, stream>>>(feat, attn_l, attn_r, el, er);
  k_gat<<<gW, 256, 0, stream>>>(row_start, deg, csr_src, el, er, feat, resval,
                                gat_bias, conv_w, conv_b, h0, hcur);

  // resval is dead now; res2 (f32) reuses its space
  k_gemm_nt_bias_relu<<<gM, 256, 0, stream>>>(node_feats, W_res, b_res, res2);

  k_gather<<<gW, 256, 0, stream>>>(row_start, deg, csr_src, hcur, nrm, h0, hnxt);
  k_gather<<<gW, 256, 0, stream>>>(row_start, deg, csr_src, hnxt, nrm, h0, hcur);
  k_gather<<<gW, 256, 0, stream>>>(row_start, deg, csr_src, hcur, nrm, h0, hnxt);
  k_gather<<<gW, 256, 0, stream>>>(row_start, deg, csr_src, hnxt, nrm, h0, hcur);
  k_gather<<<gW, 256, 0, stream>>>(row_start, deg, csr_src, hcur, nrm, h0, hnxt);

  k_finred<<<gM, 256, 0, stream>>>(hnxt, res2, h0, bn);
  k_bnstats<<<1, 64, 0, stream>>>(bn, gamma, beta, bn + 128);
  k_bnapply<<<gV, 256, 0, stream>>>(h0, bn + 128, out);
}

// Round 3
// 1003.278 us; speedup vs baseline: 1.2858x; 1.2858x over previous
//
#include <hip/hip_runtime.h>
#include <math.h>

#define NN 100000
#define NE 1600000
#define NEG_SLOPE 0.2f

typedef __attribute__((ext_vector_type(8))) short bf16x8;
typedef __attribute__((ext_vector_type(4))) float f32x4;

__device__ __forceinline__ float b2f(unsigned short u) {
  union { unsigned u; float f; } c; c.u = ((unsigned)u) << 16; return c.f;
}
__device__ __forceinline__ unsigned short f2b(float x) {
  union { float f; unsigned u; } c; c.f = x;
  unsigned r = c.u + 0x7FFFu + ((c.u >> 16) & 1u);
  return (unsigned short)(r >> 16);
}
__device__ __forceinline__ float wred(float v) {
#pragma unroll
  for (int off = 32; off > 0; off >>= 1) v += __shfl_xor(v, off, 64);
  return v;
}
__device__ __forceinline__ void fma4(float4& acc, float s, const float4& b) {
  acc.x = fmaf(s, b.x, acc.x);
  acc.y = fmaf(s, b.y, acc.y);
  acc.z = fmaf(s, b.z, acc.z);
  acc.w = fmaf(s, b.w, acc.w);
}

// ---------------- utility ----------------
__global__ __launch_bounds__(256) void k_zero(int* __restrict__ p, int nwords) {
  int i = blockIdx.x * 256 + threadIdx.x;
  if (i < nwords) p[i] = 0;
}

__global__ __launch_bounds__(256) void k_cast(const float* __restrict__ A, unsigned short* __restrict__ Ab) {
  int i = blockIdx.x * 256 + threadIdx.x;
  int i4 = i * 4;
  if (i4 < NN * 128) {
    float4 v = *(const float4*)&A[i4];
    ushort4 o; o.x = f2b(v.x); o.y = f2b(v.y); o.z = f2b(v.z); o.w = f2b(v.w);
    *(ushort4*)&Ab[i4] = o;
  }
}

// ---------------- CSR build (unordered within row) ----------------
__global__ __launch_bounds__(256) void k_deg(const int* __restrict__ dst, int* __restrict__ deg) {
  int i = blockIdx.x * 256 + threadIdx.x;
  if (i < NE) atomicAdd(&deg[dst[i]], 1);
}

__global__ __launch_bounds__(256) void k_alloc(const int* __restrict__ deg, int* __restrict__ row_start,
                                               int* __restrict__ counter, float* __restrict__ nrm) {
  int i = blockIdx.x * 256 + threadIdx.x;
  if (i < NN) {
    row_start[i] = atomicAdd(counter, deg[i]);
    nrm[i] = rsqrtf(fmaxf((float)deg[i], 1.0f));
  }
}

__global__ __launch_bounds__(256) void k_scatter(const int* __restrict__ src, const int* __restrict__ dst,
                                                 const int* __restrict__ row_start, int* __restrict__ cursor,
                                                 int* __restrict__ csr_src) {
  int i = blockIdx.x * 256 + threadIdx.x;
  if (i < NE) {
    int n = dst[i];
    int p = atomicAdd(&cursor[n], 1);
    csr_src[row_start[n] + p] = src[i];
  }
}

// ---------------- pre-pack B (both weight mats) into MFMA fragment order ----------------
// Output slab y in [0,4): half=y>>1 (W_fc / W_res_gat), colbase=(y&1)*128 in PERMUTED col space.
// Permutation: out col p in [0,256) -> (d=p>>2, h=p&3) -> source col h*64+d  (interleaved (d,h) layout).
__global__ __launch_bounds__(256) void k_prepB(const float* __restrict__ W_fc, const float* __restrict__ W_rg,
                                               unsigned short* __restrict__ Bp) {
  int y = blockIdx.y;
  const float* Bsrc = (y >> 1) ? W_rg : W_fc;
  int colbase = (y & 1) * 128;
  for (int e = blockIdx.x * 256 + threadIdx.x; e < 16384; e += 2048) {
    int n = e & 127, k = e >> 7;
    int p = colbase + n;
    int d = p >> 2, hh = p & 3;
    float v = Bsrc[k * 256 + hh * 64 + d];
    int nt = n >> 4, nn = n & 15, kt = k >> 5, quad = (k >> 3) & 3, j = k & 7;
    Bp[(size_t)y * 16384 + ((nt * 4 + kt) * 64 + quad * 16 + nn) * 8 + j] = f2b(v);
  }
}

// ---------------- merged bf16 MFMA GEMM: [feat2 | resval2] = Abf * [W_fc | W_res_gat] ----------------
// Block: 256 thr = 4 waves, tile 128 rows x 128 (permuted) cols, K=128.
// Swap trick: mfma(bfrag, afrag) -> D^T, so lane stores ushort4 of 4 consecutive out cols.
__global__ __launch_bounds__(256) void k_gemm_mfma(const unsigned short* __restrict__ Abf,
                                                   const unsigned short* __restrict__ Bp,
                                                   unsigned short* __restrict__ feat2,
                                                   unsigned short* __restrict__ resval2) {
  __shared__ unsigned short Bl[16384];  // 32 KB: fragment-ordered B tile
  int tid = threadIdx.x;
  unsigned short* Cdst = (blockIdx.y >> 1) ? resval2 : feat2;
  int colbase = (blockIdx.y & 1) * 128;
  {
    const uint4* src = (const uint4*)(Bp + (size_t)blockIdx.y * 16384);
    uint4* dst4 = (uint4*)Bl;
#pragma unroll
    for (int i = 0; i < 8; ++i) dst4[tid + i * 256] = src[tid + i * 256];
  }
  __syncthreads();
  int w = tid >> 6, lane = tid & 63;
  int quad = lane >> 4;
  int row0 = blockIdx.x * 128;
  int mrow = row0 + (lane & 15);
  f32x4 acc[8][2];
#pragma unroll
  for (int rt = 0; rt < 8; ++rt)
#pragma unroll
    for (int c = 0; c < 2; ++c) acc[rt][c] = (f32x4){0.f, 0.f, 0.f, 0.f};
#pragma unroll
  for (int kt = 0; kt < 4; ++kt) {
    bf16x8 b0 = *(const bf16x8*)&Bl[(((w * 2 + 0) * 4 + kt) * 64 + lane) * 8];
    bf16x8 b1 = *(const bf16x8*)&Bl[(((w * 2 + 1) * 4 + kt) * 64 + lane) * 8];
    int kb = kt * 32 + quad * 8;
#pragma unroll
    for (int rt = 0; rt < 8; ++rt) {
      int rr = mrow + rt * 16; if (rr > NN - 1) rr = NN - 1;
      bf16x8 a = *(const bf16x8*)&Abf[(size_t)rr * 128 + kb];
      acc[rt][0] = __builtin_amdgcn_mfma_f32_16x16x32_bf16(b0, a, acc[rt][0], 0, 0, 0);
      acc[rt][1] = __builtin_amdgcn_mfma_f32_16x16x32_bf16(b1, a, acc[rt][1], 0, 0, 0);
    }
  }
#pragma unroll
  for (int rt = 0; rt < 8; ++rt) {
    int m = row0 + rt * 16 + (lane & 15);
    if (m < NN) {
#pragma unroll
      for (int c = 0; c < 2; ++c) {
        int col = colbase + (w * 2 + c) * 16 + quad * 4;
        ushort4 o;
        o.x = f2b(acc[rt][c][0]); o.y = f2b(acc[rt][c][1]);
        o.z = f2b(acc[rt][c][2]); o.w = f2b(acc[rt][c][3]);
        *(ushort4*)&Cdst[(size_t)m * 256 + col] = o;
      }
    }
  }
}

// ---------------- res2_f32[N x 64] = relu(A[N x 128] * W_res^T + b_res) (fp32 VALU) ----------------
__global__ __launch_bounds__(256) void k_gemm_nt_bias_relu(const float* __restrict__ A, const float* __restrict__ B,
                                                           const float* __restrict__ bias, float* __restrict__ C) {
  __shared__ float Bl[128][68];
  for (int idx = threadIdx.x; idx < 64 * 128; idx += 256) {
    int d = idx >> 7, k = idx & 127;
    Bl[k][d] = B[d * 128 + k];
  }
  __syncthreads();
  int tx = threadIdx.x & 15, ty = threadIdx.x >> 4;
  int row0 = blockIdx.x * 64 + ty * 4;
  const float* ap[4];
#pragma unroll
  for (int r = 0; r < 4; ++r) ap[r] = A + (size_t)min(row0 + r, NN - 1) * 128;
  float4 acc[4];
#pragma unroll
  for (int r = 0; r < 4; ++r) acc[r] = make_float4(0.f, 0.f, 0.f, 0.f);
#pragma unroll 2
  for (int k0 = 0; k0 < 128; k0 += 4) {
    float4 b0 = *(const float4*)&Bl[k0][tx * 4];
    float4 b1 = *(const float4*)&Bl[k0 + 1][tx * 4];
    float4 b2 = *(const float4*)&Bl[k0 + 2][tx * 4];
    float4 b3 = *(const float4*)&Bl[k0 + 3][tx * 4];
#pragma unroll
    for (int r = 0; r < 4; ++r) {
      float4 a = *(const float4*)(ap[r] + k0);
      fma4(acc[r], a.x, b0); fma4(acc[r], a.y, b1);
      fma4(acc[r], a.z, b2); fma4(acc[r], a.w, b3);
    }
  }
  float4 bv = *(const float4*)&bias[tx * 4];
#pragma unroll
  for (int r = 0; r < 4; ++r) {
    int row = row0 + r;
    if (row < NN) {
      float4 v;
      v.x = fmaxf(acc[r].x + bv.x, 0.f);
      v.y = fmaxf(acc[r].y + bv.y, 0.f);
      v.z = fmaxf(acc[r].z + bv.z, 0.f);
      v.w = fmaxf(acc[r].w + bv.w, 0.f);
      *(float4*)&C[(size_t)row * 64 + tx * 4] = v;
    }
  }
}

// ---------------- el/er from interleaved feat2 ----------------
__global__ __launch_bounds__(256) void k_elr(const unsigned short* __restrict__ feat2, const float* __restrict__ al,
                                             const float* __restrict__ ar, float* __restrict__ el,
                                             float* __restrict__ er) {
  int n = blockIdx.x * 4 + (threadIdx.x >> 6);
  int lane = threadIdx.x & 63;
  if (n >= NN) return;
  ushort4 v = *(const ushort4*)&feat2[(size_t)n * 256 + lane * 4];
  float v0 = b2f(v.x), v1 = b2f(v.y), v2 = b2f(v.z), v3 = b2f(v.w);
  float l0 = wred(v0 * al[lane]);       float r0 = wred(v0 * ar[lane]);
  float l1 = wred(v1 * al[64 + lane]);  float r1 = wred(v1 * ar[64 + lane]);
  float l2 = wred(v2 * al[128 + lane]); float r2 = wred(v2 * ar[128 + lane]);
  float l3 = wred(v3 * al[192 + lane]); float r3 = wred(v3 * ar[192 + lane]);
  if (lane == 0) {
    *(float4*)&el[n * 4] = make_float4(l0, l1, l2, l3);
    *(float4*)&er[n * 4] = make_float4(r0, r1, r2, r3);
  }
}

// ---------------- fused edge-softmax + aggregation + relu + head-mix conv ----------------
__global__ __launch_bounds__(256) void k_gat(const int* __restrict__ row_start, const int* __restrict__ deg,
                                             const int* __restrict__ csr_src, const float* __restrict__ el,
                                             const float* __restrict__ er, const unsigned short* __restrict__ feat2,
                                             const unsigned short* __restrict__ resval2,
                                             const float* __restrict__ gat_bias, const float* __restrict__ conv_w,
                                             const float* __restrict__ conv_b, const float* __restrict__ nrm,
                                             float* __restrict__ h0, unsigned short* __restrict__ hsA) {
  int n = blockIdx.x * 4 + (threadIdx.x >> 6);
  int lane = threadIdx.x & 63;
  if (n >= NN) return;
  int s0 = row_start[n], cnt = deg[n];
  float4 er4 = *(const float4*)&er[n * 4];
  float acc0 = 0.f, acc1 = 0.f, acc2 = 0.f, acc3 = 0.f;
  float den0 = 0.f, den1 = 0.f, den2 = 0.f, den3 = 0.f;
  for (int base = 0; base < cnt; base += 64) {
    int j = base + lane;
    int s = 0;
    float x0 = 0.f, x1 = 0.f, x2 = 0.f, x3 = 0.f;
    if (j < cnt) {
      s = csr_src[s0 + j];
      float4 el4 = *(const float4*)&el[s * 4];
      float e0 = el4.x + er4.x; e0 = (e0 > 0.f) ? e0 : NEG_SLOPE * e0;
      float e1 = el4.y + er4.y; e1 = (e1 > 0.f) ? e1 : NEG_SLOPE * e1;
      float e2 = el4.z + er4.z; e2 = (e2 > 0.f) ? e2 : NEG_SLOPE * e2;
      float e3 = el4.w + er4.w; e3 = (e3 > 0.f) ? e3 : NEG_SLOPE * e3;
      x0 = __expf(e0); x1 = __expf(e1); x2 = __expf(e2); x3 = __expf(e3);
      den0 += x0; den1 += x1; den2 += x2; den3 += x3;
    }
    int m = cnt - base; if (m > 64) m = 64;
    for (int t = 0; t < m; ++t) {
      int ss = __shfl(s, t, 64);
      float a0 = __shfl(x0, t, 64);
      float a1 = __shfl(x1, t, 64);
      float a2 = __shfl(x2, t, 64);
      float a3 = __shfl(x3, t, 64);
      ushort4 fv = *(const ushort4*)&feat2[(size_t)ss * 256 + lane * 4];
      acc0 = fmaf(a0, b2f(fv.x), acc0);
      acc1 = fmaf(a1, b2f(fv.y), acc1);
      acc2 = fmaf(a2, b2f(fv.z), acc2);
      acc3 = fmaf(a3, b2f(fv.w), acc3);
    }
  }
  den0 = wred(den0); den1 = wred(den1); den2 = wred(den2); den3 = wred(den3);
  float i0 = 1.f / fmaxf(den0, 1e-9f);
  float i1 = 1.f / fmaxf(den1, 1e-9f);
  float i2 = 1.f / fmaxf(den2, 1e-9f);
  float i3 = 1.f / fmaxf(den3, 1e-9f);
  ushort4 rv = *(const ushort4*)&resval2[(size_t)n * 256 + lane * 4];
  float hmix = conv_b[0];
  float t0;
  t0 = fmaf(acc0, i0, b2f(rv.x) + gat_bias[lane]);       t0 = fmaxf(t0, 0.f); hmix = fmaf(conv_w[0], t0, hmix);
  t0 = fmaf(acc1, i1, b2f(rv.y) + gat_bias[64 + lane]);  t0 = fmaxf(t0, 0.f); hmix = fmaf(conv_w[1], t0, hmix);
  t0 = fmaf(acc2, i2, b2f(rv.z) + gat_bias[128 + lane]); t0 = fmaxf(t0, 0.f); hmix = fmaf(conv_w[2], t0, hmix);
  t0 = fmaf(acc3, i3, b2f(rv.w) + gat_bias[192 + lane]); t0 = fmaxf(t0, 0.f); hmix = fmaf(conv_w[3], t0, hmix);
  size_t o = (size_t)n * 64 + lane;
  h0[o] = hmix;
  hsA[o] = f2b(hmix * nrm[n]);
}

// ---------------- APPNP step (mid): hs_out = bf16(nrm[n]*(0.5*nrm[n]*sum hs_in[src] + 0.5*h0)) ----------------
__global__ __launch_bounds__(256) void k_gather_mid(const int* __restrict__ row_start, const int* __restrict__ deg,
                                                    const int* __restrict__ csr_src,
                                                    const unsigned short* __restrict__ hs_in,
                                                    const float* __restrict__ nrm, const float* __restrict__ h0,
                                                    unsigned short* __restrict__ hs_out) {
  int n = blockIdx.x * 4 + (threadIdx.x >> 6);
  int lane = threadIdx.x & 63;
  if (n >= NN) return;
  int s0 = row_start[n], cnt = deg[n];
  float acc = 0.f;
  for (int base = 0; base < cnt; base += 64) {
    int j = base + lane;
    int s = (j < cnt) ? csr_src[s0 + j] : 0;
    int m = cnt - base; if (m > 64) m = 64;
    int t = 0;
    for (; t + 1 < m; t += 2) {
      int ss0 = __shfl(s, t, 64);
      int ss1 = __shfl(s, t + 1, 64);
      float u0 = b2f(hs_in[(size_t)ss0 * 64 + lane]);
      float u1 = b2f(hs_in[(size_t)ss1 * 64 + lane]);
      acc += u0; acc += u1;
    }
    if (t < m) {
      int ss = __shfl(s, t, 64);
      acc += b2f(hs_in[(size_t)ss * 64 + lane]);
    }
  }
  size_t o = (size_t)n * 64 + lane;
  float nn_ = nrm[n];
  float v = fmaf(0.5f * nn_, acc, 0.5f * h0[o]);
  hs_out[o] = f2b(v * nn_);
}

// ---------------- APPNP step (last): hout = bf16(0.5*nrm[n]*sum hs_in[src] + 0.5*h0) ----------------
__global__ __launch_bounds__(256) void k_gather_last(const int* __restrict__ row_start, const int* __restrict__ deg,
                                                     const int* __restrict__ csr_src,
                                                     const unsigned short* __restrict__ hs_in,
                                                     const float* __restrict__ nrm, const float* __restrict__ h0,
                                                     unsigned short* __restrict__ hout) {
  int n = blockIdx.x * 4 + (threadIdx.x >> 6);
  int lane = threadIdx.x & 63;
  if (n >= NN) return;
  int s0 = row_start[n], cnt = deg[n];
  float acc = 0.f;
  for (int base = 0; base < cnt; base += 64) {
    int j = base + lane;
    int s = (j < cnt) ? csr_src[s0 + j] : 0;
    int m = cnt - base; if (m > 64) m = 64;
    int t = 0;
    for (; t + 1 < m; t += 2) {
      int ss0 = __shfl(s, t, 64);
      int ss1 = __shfl(s, t + 1, 64);
      float u0 = b2f(hs_in[(size_t)ss0 * 64 + lane]);
      float u1 = b2f(hs_in[(size_t)ss1 * 64 + lane]);
      acc += u0; acc += u1;
    }
    if (t < m) {
      int ss = __shfl(s, t, 64);
      acc += b2f(hs_in[(size_t)ss * 64 + lane]);
    }
  }
  size_t o = (size_t)n * 64 + lane;
  float v = fmaf(0.5f * nrm[n], acc, 0.5f * h0[o]);
  hout[o] = f2b(v);
}

// ---------------- final residual add + BN partial sums ----------------
__global__ __launch_bounds__(256) void k_finred(const unsigned short* __restrict__ hl,
                                                const float* __restrict__ res2, float* __restrict__ hfin,
                                                float* __restrict__ bn) {
  __shared__ float s1[256], s2[256];
  int d = threadIdx.x & 63;
  int rb = blockIdx.x * 64;
  float sum = 0.f, sq = 0.f;
  for (int r = threadIdx.x >> 6; r < 64; r += 4) {
    int n = rb + r;
    if (n < NN) {
      size_t idx = (size_t)n * 64 + d;
      float v = b2f(hl[idx]) + res2[idx];
      hfin[idx] = v;
      sum += v; sq += v * v;
    }
  }
  s1[threadIdx.x] = sum; s2[threadIdx.x] = sq;
  __syncthreads();
  if (threadIdx.x < 128) { s1[threadIdx.x] += s1[threadIdx.x + 128]; s2[threadIdx.x] += s2[threadIdx.x + 128]; }
  __syncthreads();
  if (threadIdx.x < 64) {
    atomicAdd(&bn[d], s1[threadIdx.x] + s1[threadIdx.x + 64]);
    atomicAdd(&bn[64 + d], s2[threadIdx.x] + s2[threadIdx.x + 64]);
  }
}

__global__ void k_bnstats(const float* __restrict__ bn, const float* __restrict__ gamma,
                          const float* __restrict__ beta, float* __restrict__ bns) {
  int d = threadIdx.x;
  float mu = bn[d] * (1.0f / NN);
  float var = fmaxf(bn[64 + d] * (1.0f / NN) - mu * mu, 0.f);
  float sc = rsqrtf(var + 1e-5f) * gamma[d];
  bns[d] = sc;
  bns[64 + d] = beta[d] - mu * sc;
}

__global__ __launch_bounds__(256) void k_bnapply(const float* __restrict__ h, const float* __restrict__ bns,
                                                 float* __restrict__ out) {
  int i = blockIdx.x * 256 + threadIdx.x;
  if (i < NN * 64) {
    int d = i & 63;
    out[i] = fmaf(h[i], bns[d], bns[64 + d]);
  }
}

extern "C" void kernel_launch(void* const* d_in, const int* in_sizes, int n_in,
                              void* d_out, int out_size, void* d_ws, size_t ws_size,
                              hipStream_t stream) {
  const float* node_feats = (const float*)d_in[0];
  const int* src = (const int*)d_in[1];
  const int* dst = (const int*)d_in[2];
  const float* W_fc = (const float*)d_in[3];
  const float* attn_l = (const float*)d_in[4];
  const float* attn_r = (const float*)d_in[5];
  const float* W_res_gat = (const float*)d_in[6];
  const float* gat_bias = (const float*)d_in[7];
  const float* conv_w = (const float*)d_in[8];
  const float* conv_b = (const float*)d_in[9];
  const float* W_res = (const float*)d_in[10];
  const float* b_res = (const float*)d_in[11];
  const float* gamma = (const float*)d_in[12];
  const float* beta = (const float*)d_in[13];
  float* out = (float*)d_out;

  char* base = (char*)d_ws;
  size_t off = 0;
  auto alloc = [&](size_t bytes) -> char* {
    char* p = base + off;
    off = (off + bytes + 255) & ~(size_t)255;
    return p;
  };
  unsigned short* feat2   = (unsigned short*)alloc((size_t)NN * 256 * 2);  // 51.2 MB, (n,d,h) interleaved
  unsigned short* resval2 = (unsigned short*)alloc((size_t)NN * 256 * 2);  // 51.2 MB; res2 f32 aliases after k_gat
  float* res2             = (float*)resval2;
  float* el               = (float*)alloc((size_t)NN * 4 * 4);
  float* er               = (float*)alloc((size_t)NN * 4 * 4);
  float* h0               = (float*)alloc((size_t)NN * 64 * 4);            // 25.6 MB; Abf aliases BEFORE k_gat; hfin aliases at end
  unsigned short* Abf     = (unsigned short*)h0;                           // NN*128 bf16 = 25.6 MB
  unsigned short* hsA     = (unsigned short*)alloc((size_t)NN * 64 * 2);   // 12.8 MB (scaled h, bf16)
  unsigned short* hsB     = (unsigned short*)alloc((size_t)NN * 64 * 2);   // 12.8 MB; hout aliases for last step
  unsigned short* hout    = hsB;
  int* csr_src            = (int*)alloc((size_t)NE * 4);                   // 6.4 MB
  float* nrm              = (float*)alloc((size_t)NN * 4);
  int* row_start          = (int*)alloc((size_t)NN * 4);
  unsigned short* Bpacked = (unsigned short*)alloc((size_t)4 * 16384 * 2); // 128 KB fragment-ordered B
  size_t zoff = off;
  int* deg                = (int*)alloc((size_t)NN * 4);
  int* cursor             = (int*)alloc((size_t)NN * 4);
  int* counter            = (int*)alloc(256);
  float* bn               = (float*)alloc(256 * 4);
  float* hfin             = h0;  // h0 dead after last gather

  int zwords = (int)((off - zoff) / 4);
  int gE = (NE + 255) / 256;
  int gN = (NN + 255) / 256;
  int gW = (NN + 3) / 4;
  int gM = (NN + 63) / 64;
  int gV = (NN * 64 + 255) / 256;

  k_zero<<<(zwords + 255) / 256, 256, 0, stream>>>((int*)(base + zoff), zwords);
  k_deg<<<gE, 256, 0, stream>>>(dst, deg);
  k_alloc<<<gN, 256, 0, stream>>>(deg, row_start, counter, nrm);
  k_scatter<<<gE, 256, 0, stream>>>(src, dst, row_start, cursor, csr_src);

  k_cast<<<(NN * 128 / 4 + 255) / 256, 256, 0, stream>>>(node_feats, Abf);
  k_prepB<<<dim3(8, 4), 256, 0, stream>>>(W_fc, W_res_gat, Bpacked);
  k_gemm_mfma<<<dim3((NN + 127) / 128, 4), 256, 0, stream>>>(Abf, Bpacked, feat2, resval2);

  k_elr<<<gW, 256, 0, stream>>>(feat2, attn_l, attn_r, el, er);
  k_gat<<<gW, 256, 0, stream>>>(row_start, deg, csr_src, el, er, feat2, resval2,
                                gat_bias, conv_w, conv_b, nrm, h0, hsA);

  // resval2 dead now; res2 (f32) reuses its space. Abf (aliased h0) was already consumed by GEMM.
  k_gemm_nt_bias_relu<<<gM, 256, 0, stream>>>(node_feats, W_res, b_res, res2);

  k_gather_mid<<<gW, 256, 0, stream>>>(row_start, deg, csr_src, hsA, nrm, h0, hsB);
  k_gather_mid<<<gW, 256, 0, stream>>>(row_start, deg, csr_src, hsB, nrm, h0, hsA);
  k_gather_mid<<<gW, 256, 0, stream>>>(row_start, deg, csr_src, hsA, nrm, h0, hsB);
  k_gather_mid<<<gW, 256, 0, stream>>>(row_start, deg, csr_src, hsB, nrm, h0, hsA);
  k_gather_last<<<gW, 256, 0, stream>>>(row_start, deg, csr_src, hsA, nrm, h0, hout);

  k_finred<<<gM, 256, 0, stream>>>(hout, res2, hfin, bn);
  k_bnstats<<<1, 64, 0, stream>>>(bn, gamma, beta, bn + 128);
  k_bnapply<<<gV, 256, 0, stream>>>(hfin, bn + 128, out);
}

// Round 4
// 907.823 us; speedup vs baseline: 1.4210x; 1.1051x over previous
//
#include <hip/hip_runtime.h>
#include <math.h>

#define NN 100000
#define NE 1600000
#define NEG_SLOPE 0.2f

typedef __attribute__((ext_vector_type(8))) short bf16x8;
typedef __attribute__((ext_vector_type(4))) float f32x4;

__device__ __forceinline__ float b2f(unsigned short u) {
  union { unsigned u; float f; } c; c.u = ((unsigned)u) << 16; return c.f;
}
__device__ __forceinline__ unsigned short f2b(float x) {
  union { float f; unsigned u; } c; c.f = x;
  unsigned r = c.u + 0x7FFFu + ((c.u >> 16) & 1u);
  return (unsigned short)(r >> 16);
}
__device__ __forceinline__ float wred(float v) {
#pragma unroll
  for (int off = 32; off > 0; off >>= 1) v += __shfl_xor(v, off, 64);
  return v;
}
__device__ __forceinline__ float readlane_f(float v, int l) {
  return __uint_as_float((unsigned)__builtin_amdgcn_readlane((int)__float_as_uint(v), l));
}
__device__ __forceinline__ void fma4(float4& acc, float s, const float4& b) {
  acc.x = fmaf(s, b.x, acc.x);
  acc.y = fmaf(s, b.y, acc.y);
  acc.z = fmaf(s, b.z, acc.z);
  acc.w = fmaf(s, b.w, acc.w);
}

// ---------------- utility ----------------
__global__ __launch_bounds__(256) void k_zero(int* __restrict__ p, int nwords) {
  int i = blockIdx.x * 256 + threadIdx.x;
  if (i < nwords) p[i] = 0;
}

// zero the two dummy rows (index NN) of the ping-pong hs buffers
__global__ void k_zrow(unsigned short* __restrict__ a, unsigned short* __restrict__ b) {
  int i = threadIdx.x;
  a[(size_t)NN * 64 + i] = 0;
  b[(size_t)NN * 64 + i] = 0;
}

__global__ __launch_bounds__(256) void k_cast(const float* __restrict__ A, unsigned short* __restrict__ Ab) {
  int i = blockIdx.x * 256 + threadIdx.x;
  int i4 = i * 4;
  if (i4 < NN * 128) {
    float4 v = *(const float4*)&A[i4];
    ushort4 o; o.x = f2b(v.x); o.y = f2b(v.y); o.z = f2b(v.z); o.w = f2b(v.w);
    *(ushort4*)&Ab[i4] = o;
  }
}

// ---------------- CSR build (unordered within row) ----------------
__global__ __launch_bounds__(256) void k_deg(const int* __restrict__ dst, int* __restrict__ deg) {
  int i = blockIdx.x * 256 + threadIdx.x;
  if (i < NE) atomicAdd(&deg[dst[i]], 1);
}

__global__ __launch_bounds__(256) void k_alloc(const int* __restrict__ deg, int* __restrict__ row_start,
                                               int* __restrict__ counter, float* __restrict__ nrm) {
  int i = blockIdx.x * 256 + threadIdx.x;
  if (i < NN) {
    row_start[i] = atomicAdd(counter, deg[i]);
    nrm[i] = rsqrtf(fmaxf((float)deg[i], 1.0f));
  }
}

__global__ __launch_bounds__(256) void k_scatter(const int* __restrict__ src, const int* __restrict__ dst,
                                                 const int* __restrict__ row_start, int* __restrict__ cursor,
                                                 int* __restrict__ csr_src) {
  int i = blockIdx.x * 256 + threadIdx.x;
  if (i < NE) {
    int n = dst[i];
    int p = atomicAdd(&cursor[n], 1);
    csr_src[row_start[n] + p] = src[i];
  }
}

// ---------------- pre-pack B (both weight mats) into MFMA fragment order ----------------
__global__ __launch_bounds__(256) void k_prepB(const float* __restrict__ W_fc, const float* __restrict__ W_rg,
                                               unsigned short* __restrict__ Bp) {
  int y = blockIdx.y;
  const float* Bsrc = (y >> 1) ? W_rg : W_fc;
  int colbase = (y & 1) * 128;
  for (int e = blockIdx.x * 256 + threadIdx.x; e < 16384; e += 2048) {
    int n = e & 127, k = e >> 7;
    int p = colbase + n;
    int d = p >> 2, hh = p & 3;
    float v = Bsrc[k * 256 + hh * 64 + d];
    int nt = n >> 4, nn = n & 15, kt = k >> 5, quad = (k >> 3) & 3, j = k & 7;
    Bp[(size_t)y * 16384 + ((nt * 4 + kt) * 64 + quad * 16 + nn) * 8 + j] = f2b(v);
  }
}

// ---------------- merged bf16 MFMA GEMM: [feat2 | resval2] = Abf * [W_fc | W_res_gat] ----------------
__global__ __launch_bounds__(256) void k_gemm_mfma(const unsigned short* __restrict__ Abf,
                                                   const unsigned short* __restrict__ Bp,
                                                   unsigned short* __restrict__ feat2,
                                                   unsigned short* __restrict__ resval2) {
  __shared__ unsigned short Bl[16384];
  int tid = threadIdx.x;
  unsigned short* Cdst = (blockIdx.y >> 1) ? resval2 : feat2;
  int colbase = (blockIdx.y & 1) * 128;
  {
    const uint4* src = (const uint4*)(Bp + (size_t)blockIdx.y * 16384);
    uint4* dst4 = (uint4*)Bl;
#pragma unroll
    for (int i = 0; i < 8; ++i) dst4[tid + i * 256] = src[tid + i * 256];
  }
  __syncthreads();
  int w = tid >> 6, lane = tid & 63;
  int quad = lane >> 4;
  int row0 = blockIdx.x * 128;
  int mrow = row0 + (lane & 15);
  f32x4 acc[8][2];
#pragma unroll
  for (int rt = 0; rt < 8; ++rt)
#pragma unroll
    for (int c = 0; c < 2; ++c) acc[rt][c] = (f32x4){0.f, 0.f, 0.f, 0.f};
#pragma unroll
  for (int kt = 0; kt < 4; ++kt) {
    bf16x8 b0 = *(const bf16x8*)&Bl[(((w * 2 + 0) * 4 + kt) * 64 + lane) * 8];
    bf16x8 b1 = *(const bf16x8*)&Bl[(((w * 2 + 1) * 4 + kt) * 64 + lane) * 8];
    int kb = kt * 32 + quad * 8;
#pragma unroll
    for (int rt = 0; rt < 8; ++rt) {
      int rr = mrow + rt * 16; if (rr > NN - 1) rr = NN - 1;
      bf16x8 a = *(const bf16x8*)&Abf[(size_t)rr * 128 + kb];
      acc[rt][0] = __builtin_amdgcn_mfma_f32_16x16x32_bf16(b0, a, acc[rt][0], 0, 0, 0);
      acc[rt][1] = __builtin_amdgcn_mfma_f32_16x16x32_bf16(b1, a, acc[rt][1], 0, 0, 0);
    }
  }
#pragma unroll
  for (int rt = 0; rt < 8; ++rt) {
    int m = row0 + rt * 16 + (lane & 15);
    if (m < NN) {
#pragma unroll
      for (int c = 0; c < 2; ++c) {
        int col = colbase + (w * 2 + c) * 16 + quad * 4;
        ushort4 o;
        o.x = f2b(acc[rt][c][0]); o.y = f2b(acc[rt][c][1]);
        o.z = f2b(acc[rt][c][2]); o.w = f2b(acc[rt][c][3]);
        *(ushort4*)&Cdst[(size_t)m * 256 + col] = o;
      }
    }
  }
}

// ---------------- res2_f32[N x 64] = relu(A[N x 128] * W_res^T + b_res) (fp32 VALU) ----------------
__global__ __launch_bounds__(256) void k_gemm_nt_bias_relu(const float* __restrict__ A, const float* __restrict__ B,
                                                           const float* __restrict__ bias, float* __restrict__ C) {
  __shared__ float Bl[128][68];
  for (int idx = threadIdx.x; idx < 64 * 128; idx += 256) {
    int d = idx >> 7, k = idx & 127;
    Bl[k][d] = B[d * 128 + k];
  }
  __syncthreads();
  int tx = threadIdx.x & 15, ty = threadIdx.x >> 4;
  int row0 = blockIdx.x * 64 + ty * 4;
  const float* ap[4];
#pragma unroll
  for (int r = 0; r < 4; ++r) ap[r] = A + (size_t)min(row0 + r, NN - 1) * 128;
  float4 acc[4];
#pragma unroll
  for (int r = 0; r < 4; ++r) acc[r] = make_float4(0.f, 0.f, 0.f, 0.f);
#pragma unroll 2
  for (int k0 = 0; k0 < 128; k0 += 4) {
    float4 b0 = *(const float4*)&Bl[k0][tx * 4];
    float4 b1 = *(const float4*)&Bl[k0 + 1][tx * 4];
    float4 b2 = *(const float4*)&Bl[k0 + 2][tx * 4];
    float4 b3 = *(const float4*)&Bl[k0 + 3][tx * 4];
#pragma unroll
    for (int r = 0; r < 4; ++r) {
      float4 a = *(const float4*)(ap[r] + k0);
      fma4(acc[r], a.x, b0); fma4(acc[r], a.y, b1);
      fma4(acc[r], a.z, b2); fma4(acc[r], a.w, b3);
    }
  }
  float4 bv = *(const float4*)&bias[tx * 4];
#pragma unroll
  for (int r = 0; r < 4; ++r) {
    int row = row0 + r;
    if (row < NN) {
      float4 v;
      v.x = fmaxf(acc[r].x + bv.x, 0.f);
      v.y = fmaxf(acc[r].y + bv.y, 0.f);
      v.z = fmaxf(acc[r].z + bv.z, 0.f);
      v.w = fmaxf(acc[r].w + bv.w, 0.f);
      *(float4*)&C[(size_t)row * 64 + tx * 4] = v;
    }
  }
}

// ---------------- el/er from interleaved feat2 ----------------
__global__ __launch_bounds__(256) void k_elr(const unsigned short* __restrict__ feat2, const float* __restrict__ al,
                                             const float* __restrict__ ar, float* __restrict__ el,
                                             float* __restrict__ er) {
  int n = blockIdx.x * 4 + (threadIdx.x >> 6);
  int lane = threadIdx.x & 63;
  if (n >= NN) return;
  ushort4 v = *(const ushort4*)&feat2[(size_t)n * 256 + lane * 4];
  float v0 = b2f(v.x), v1 = b2f(v.y), v2 = b2f(v.z), v3 = b2f(v.w);
  float l0 = wred(v0 * al[lane]);       float r0 = wred(v0 * ar[lane]);
  float l1 = wred(v1 * al[64 + lane]);  float r1 = wred(v1 * ar[64 + lane]);
  float l2 = wred(v2 * al[128 + lane]); float r2 = wred(v2 * ar[128 + lane]);
  float l3 = wred(v3 * al[192 + lane]); float r3 = wred(v3 * ar[192 + lane]);
  if (lane == 0) {
    *(float4*)&el[n * 4] = make_float4(l0, l1, l2, l3);
    *(float4*)&er[n * 4] = make_float4(r0, r1, r2, r3);
  }
}

// ---------------- fused edge-softmax + aggregation + relu + head-mix conv ----------------
// readlane broadcast (SGPR) instead of ds_bpermute; 4-edge pipelined inner loop.
// Lanes t in [m, mr) carry x==0 so no guards needed after rounding up to x4.
__global__ __launch_bounds__(256) void k_gat(const int* __restrict__ row_start, const int* __restrict__ deg,
                                             const int* __restrict__ csr_src, const float* __restrict__ el,
                                             const float* __restrict__ er, const unsigned short* __restrict__ feat2,
                                             const unsigned short* __restrict__ resval2,
                                             const float* __restrict__ gat_bias, const float* __restrict__ conv_w,
                                             const float* __restrict__ conv_b, const float* __restrict__ nrm,
                                             float* __restrict__ h0, unsigned short* __restrict__ hsA) {
  int n = blockIdx.x * 4 + (threadIdx.x >> 6);
  int lane = threadIdx.x & 63;
  if (n >= NN) return;
  int s0 = row_start[n], cnt = deg[n];
  float4 er4 = *(const float4*)&er[n * 4];
  float acc0 = 0.f, acc1 = 0.f, acc2 = 0.f, acc3 = 0.f;
  float den0 = 0.f, den1 = 0.f, den2 = 0.f, den3 = 0.f;
  for (int base = 0; base < cnt; base += 64) {
    int j = base + lane;
    int s = 0;
    float x0 = 0.f, x1 = 0.f, x2 = 0.f, x3 = 0.f;
    if (j < cnt) {
      s = csr_src[s0 + j];
      float4 el4 = *(const float4*)&el[s * 4];
      float e0 = el4.x + er4.x; e0 = (e0 > 0.f) ? e0 : NEG_SLOPE * e0;
      float e1 = el4.y + er4.y; e1 = (e1 > 0.f) ? e1 : NEG_SLOPE * e1;
      float e2 = el4.z + er4.z; e2 = (e2 > 0.f) ? e2 : NEG_SLOPE * e2;
      float e3 = el4.w + er4.w; e3 = (e3 > 0.f) ? e3 : NEG_SLOPE * e3;
      x0 = __expf(e0); x1 = __expf(e1); x2 = __expf(e2); x3 = __expf(e3);
      den0 += x0; den1 += x1; den2 += x2; den3 += x3;
    }
    int m = cnt - base; if (m > 64) m = 64;
    int mr = (m + 3) & ~3;
    for (int t = 0; t < mr; t += 4) {
      int ss0 = __builtin_amdgcn_readlane(s, t);
      int ss1 = __builtin_amdgcn_readlane(s, t + 1);
      int ss2 = __builtin_amdgcn_readlane(s, t + 2);
      int ss3 = __builtin_amdgcn_readlane(s, t + 3);
      uint2 f0 = *(const uint2*)&feat2[(size_t)ss0 * 256 + lane * 4];
      uint2 f1 = *(const uint2*)&feat2[(size_t)ss1 * 256 + lane * 4];
      uint2 f2 = *(const uint2*)&feat2[(size_t)ss2 * 256 + lane * 4];
      uint2 f3 = *(const uint2*)&feat2[(size_t)ss3 * 256 + lane * 4];
      float a00 = readlane_f(x0, t),     a10 = readlane_f(x1, t),     a20 = readlane_f(x2, t),     a30 = readlane_f(x3, t);
      float a01 = readlane_f(x0, t + 1), a11 = readlane_f(x1, t + 1), a21 = readlane_f(x2, t + 1), a31 = readlane_f(x3, t + 1);
      float a02 = readlane_f(x0, t + 2), a12 = readlane_f(x1, t + 2), a22 = readlane_f(x2, t + 2), a32 = readlane_f(x3, t + 2);
      float a03 = readlane_f(x0, t + 3), a13 = readlane_f(x1, t + 3), a23 = readlane_f(x2, t + 3), a33 = readlane_f(x3, t + 3);
      acc0 = fmaf(a00, __uint_as_float(f0.x << 16), acc0);
      acc1 = fmaf(a10, __uint_as_float(f0.x & 0xffff0000u), acc1);
      acc2 = fmaf(a20, __uint_as_float(f0.y << 16), acc2);
      acc3 = fmaf(a30, __uint_as_float(f0.y & 0xffff0000u), acc3);
      acc0 = fmaf(a01, __uint_as_float(f1.x << 16), acc0);
      acc1 = fmaf(a11, __uint_as_float(f1.x & 0xffff0000u), acc1);
      acc2 = fmaf(a21, __uint_as_float(f1.y << 16), acc2);
      acc3 = fmaf(a31, __uint_as_float(f1.y & 0xffff0000u), acc3);
      acc0 = fmaf(a02, __uint_as_float(f2.x << 16), acc0);
      acc1 = fmaf(a12, __uint_as_float(f2.x & 0xffff0000u), acc1);
      acc2 = fmaf(a22, __uint_as_float(f2.y << 16), acc2);
      acc3 = fmaf(a32, __uint_as_float(f2.y & 0xffff0000u), acc3);
      acc0 = fmaf(a03, __uint_as_float(f3.x << 16), acc0);
      acc1 = fmaf(a13, __uint_as_float(f3.x & 0xffff0000u), acc1);
      acc2 = fmaf(a23, __uint_as_float(f3.y << 16), acc2);
      acc3 = fmaf(a33, __uint_as_float(f3.y & 0xffff0000u), acc3);
    }
  }
  den0 = wred(den0); den1 = wred(den1); den2 = wred(den2); den3 = wred(den3);
  float i0 = 1.f / fmaxf(den0, 1e-9f);
  float i1 = 1.f / fmaxf(den1, 1e-9f);
  float i2 = 1.f / fmaxf(den2, 1e-9f);
  float i3 = 1.f / fmaxf(den3, 1e-9f);
  ushort4 rv = *(const ushort4*)&resval2[(size_t)n * 256 + lane * 4];
  float hmix = conv_b[0];
  float t0;
  t0 = fmaf(acc0, i0, b2f(rv.x) + gat_bias[lane]);       t0 = fmaxf(t0, 0.f); hmix = fmaf(conv_w[0], t0, hmix);
  t0 = fmaf(acc1, i1, b2f(rv.y) + gat_bias[64 + lane]);  t0 = fmaxf(t0, 0.f); hmix = fmaf(conv_w[1], t0, hmix);
  t0 = fmaf(acc2, i2, b2f(rv.z) + gat_bias[128 + lane]); t0 = fmaxf(t0, 0.f); hmix = fmaf(conv_w[2], t0, hmix);
  t0 = fmaf(acc3, i3, b2f(rv.w) + gat_bias[192 + lane]); t0 = fmaxf(t0, 0.f); hmix = fmaf(conv_w[3], t0, hmix);
  size_t o = (size_t)n * 64 + lane;
  h0[o] = hmix;
  hsA[o] = f2b(hmix * nrm[n]);
}

// ---------------- APPNP step (mid): hs_out = bf16(nrm[n]*(0.5*nrm[n]*sum hs_in[src] + 0.5*h0)) ----------------
// OOB lanes point at zeroed dummy row NN; readlane + scalar-addressed loads, 4-deep pipeline.
__global__ __launch_bounds__(256) void k_gather_mid(const int* __restrict__ row_start, const int* __restrict__ deg,
                                                    const int* __restrict__ csr_src,
                                                    const unsigned short* __restrict__ hs_in,
                                                    const float* __restrict__ nrm, const float* __restrict__ h0,
                                                    unsigned short* __restrict__ hs_out) {
  int n = blockIdx.x * 4 + (threadIdx.x >> 6);
  int lane = threadIdx.x & 63;
  if (n >= NN) return;
  int s0 = row_start[n], cnt = deg[n];
  float acc = 0.f;
  for (int base = 0; base < cnt; base += 64) {
    int j = base + lane;
    int s = (j < cnt) ? csr_src[s0 + j] : NN;
    int m = cnt - base; if (m > 64) m = 64;
    int mr = (m + 3) & ~3;
    for (int t = 0; t < mr; t += 4) {
      int ss0 = __builtin_amdgcn_readlane(s, t);
      int ss1 = __builtin_amdgcn_readlane(s, t + 1);
      int ss2 = __builtin_amdgcn_readlane(s, t + 2);
      int ss3 = __builtin_amdgcn_readlane(s, t + 3);
      float u0 = b2f(hs_in[(size_t)ss0 * 64 + lane]);
      float u1 = b2f(hs_in[(size_t)ss1 * 64 + lane]);
      float u2 = b2f(hs_in[(size_t)ss2 * 64 + lane]);
      float u3 = b2f(hs_in[(size_t)ss3 * 64 + lane]);
      acc += (u0 + u1) + (u2 + u3);
    }
  }
  size_t o = (size_t)n * 64 + lane;
  float nn_ = nrm[n];
  float v = fmaf(0.5f * nn_, acc, 0.5f * h0[o]);
  hs_out[o] = f2b(v * nn_);
}

// ---------------- APPNP step (last): hout = bf16(0.5*nrm[n]*sum hs_in[src] + 0.5*h0) ----------------
__global__ __launch_bounds__(256) void k_gather_last(const int* __restrict__ row_start, const int* __restrict__ deg,
                                                     const int* __restrict__ csr_src,
                                                     const unsigned short* __restrict__ hs_in,
                                                     const float* __restrict__ nrm, const float* __restrict__ h0,
                                                     unsigned short* __restrict__ hout) {
  int n = blockIdx.x * 4 + (threadIdx.x >> 6);
  int lane = threadIdx.x & 63;
  if (n >= NN) return;
  int s0 = row_start[n], cnt = deg[n];
  float acc = 0.f;
  for (int base = 0; base < cnt; base += 64) {
    int j = base + lane;
    int s = (j < cnt) ? csr_src[s0 + j] : NN;
    int m = cnt - base; if (m > 64) m = 64;
    int mr = (m + 3) & ~3;
    for (int t = 0; t < mr; t += 4) {
      int ss0 = __builtin_amdgcn_readlane(s, t);
      int ss1 = __builtin_amdgcn_readlane(s, t + 1);
      int ss2 = __builtin_amdgcn_readlane(s, t + 2);
      int ss3 = __builtin_amdgcn_readlane(s, t + 3);
      float u0 = b2f(hs_in[(size_t)ss0 * 64 + lane]);
      float u1 = b2f(hs_in[(size_t)ss1 * 64 + lane]);
      float u2 = b2f(hs_in[(size_t)ss2 * 64 + lane]);
      float u3 = b2f(hs_in[(size_t)ss3 * 64 + lane]);
      acc += (u0 + u1) + (u2 + u3);
    }
  }
  size_t o = (size_t)n * 64 + lane;
  float v = fmaf(0.5f * nrm[n], acc, 0.5f * h0[o]);
  hout[o] = f2b(v);
}

// ---------------- final residual add + BN partial sums ----------------
__global__ __launch_bounds__(256) void k_finred(const unsigned short* __restrict__ hl,
                                                const float* __restrict__ res2, float* __restrict__ hfin,
                                                float* __restrict__ bn) {
  __shared__ float s1[256], s2[256];
  int d = threadIdx.x & 63;
  int rb = blockIdx.x * 64;
  float sum = 0.f, sq = 0.f;
  for (int r = threadIdx.x >> 6; r < 64; r += 4) {
    int n = rb + r;
    if (n < NN) {
      size_t idx = (size_t)n * 64 + d;
      float v = b2f(hl[idx]) + res2[idx];
      hfin[idx] = v;
      sum += v; sq += v * v;
    }
  }
  s1[threadIdx.x] = sum; s2[threadIdx.x] = sq;
  __syncthreads();
  if (threadIdx.x < 128) { s1[threadIdx.x] += s1[threadIdx.x + 128]; s2[threadIdx.x] += s2[threadIdx.x + 128]; }
  __syncthreads();
  if (threadIdx.x < 64) {
    atomicAdd(&bn[d], s1[threadIdx.x] + s1[threadIdx.x + 64]);
    atomicAdd(&bn[64 + d], s2[threadIdx.x] + s2[threadIdx.x + 64]);
  }
}

__global__ void k_bnstats(const float* __restrict__ bn, const float* __restrict__ gamma,
                          const float* __restrict__ beta, float* __restrict__ bns) {
  int d = threadIdx.x;
  float mu = bn[d] * (1.0f / NN);
  float var = fmaxf(bn[64 + d] * (1.0f / NN) - mu * mu, 0.f);
  float sc = rsqrtf(var + 1e-5f) * gamma[d];
  bns[d] = sc;
  bns[64 + d] = beta[d] - mu * sc;
}

__global__ __launch_bounds__(256) void k_bnapply(const float* __restrict__ h, const float* __restrict__ bns,
                                                 float* __restrict__ out) {
  int i = blockIdx.x * 256 + threadIdx.x;
  if (i < NN * 64) {
    int d = i & 63;
    out[i] = fmaf(h[i], bns[d], bns[64 + d]);
  }
}

extern "C" void kernel_launch(void* const* d_in, const int* in_sizes, int n_in,
                              void* d_out, int out_size, void* d_ws, size_t ws_size,
                              hipStream_t stream) {
  const float* node_feats = (const float*)d_in[0];
  const int* src = (const int*)d_in[1];
  const int* dst = (const int*)d_in[2];
  const float* W_fc = (const float*)d_in[3];
  const float* attn_l = (const float*)d_in[4];
  const float* attn_r = (const float*)d_in[5];
  const float* W_res_gat = (const float*)d_in[6];
  const float* gat_bias = (const float*)d_in[7];
  const float* conv_w = (const float*)d_in[8];
  const float* conv_b = (const float*)d_in[9];
  const float* W_res = (const float*)d_in[10];
  const float* b_res = (const float*)d_in[11];
  const float* gamma = (const float*)d_in[12];
  const float* beta = (const float*)d_in[13];
  float* out = (float*)d_out;

  char* base = (char*)d_ws;
  size_t off = 0;
  auto alloc = [&](size_t bytes) -> char* {
    char* p = base + off;
    off = (off + bytes + 255) & ~(size_t)255;
    return p;
  };
  unsigned short* feat2   = (unsigned short*)alloc((size_t)NN * 256 * 2);        // 51.2 MB, (n,d,h) interleaved
  unsigned short* resval2 = (unsigned short*)alloc((size_t)NN * 256 * 2);        // 51.2 MB; res2 f32 aliases after k_gat
  float* res2             = (float*)resval2;
  float* el               = (float*)alloc((size_t)NN * 4 * 4);
  float* er               = (float*)alloc((size_t)NN * 4 * 4);
  float* h0               = (float*)alloc((size_t)NN * 64 * 4);                  // 25.6 MB; Abf aliases BEFORE k_gat; hfin at end
  unsigned short* Abf     = (unsigned short*)h0;
  unsigned short* hsA     = (unsigned short*)alloc((size_t)(NN + 1) * 64 * 2);   // +dummy zero row NN
  unsigned short* hsB     = (unsigned short*)alloc((size_t)(NN + 1) * 64 * 2);
  unsigned short* hout    = hsB;
  int* csr_src            = (int*)alloc((size_t)NE * 4);
  float* nrm              = (float*)alloc((size_t)NN * 4);
  int* row_start          = (int*)alloc((size_t)NN * 4);
  unsigned short* Bpacked = (unsigned short*)alloc((size_t)4 * 16384 * 2);
  size_t zoff = off;
  int* deg                = (int*)alloc((size_t)NN * 4);
  int* cursor             = (int*)alloc((size_t)NN * 4);
  int* counter            = (int*)alloc(256);
  float* bn               = (float*)alloc(256 * 4);
  float* hfin             = h0;

  int zwords = (int)((off - zoff) / 4);
  int gE = (NE + 255) / 256;
  int gN = (NN + 255) / 256;
  int gW = (NN + 3) / 4;
  int gM = (NN + 63) / 64;
  int gV = (NN * 64 + 255) / 256;

  k_zero<<<(zwords + 255) / 256, 256, 0, stream>>>((int*)(base + zoff), zwords);
  k_zrow<<<1, 64, 0, stream>>>(hsA, hsB);
  k_deg<<<gE, 256, 0, stream>>>(dst, deg);
  k_alloc<<<gN, 256, 0, stream>>>(deg, row_start, counter, nrm);
  k_scatter<<<gE, 256, 0, stream>>>(src, dst, row_start, cursor, csr_src);

  k_cast<<<(NN * 128 / 4 + 255) / 256, 256, 0, stream>>>(node_feats, Abf);
  k_prepB<<<dim3(8, 4), 256, 0, stream>>>(W_fc, W_res_gat, Bpacked);
  k_gemm_mfma<<<dim3((NN + 127) / 128, 4), 256, 0, stream>>>(Abf, Bpacked, feat2, resval2);

  k_elr<<<gW, 256, 0, stream>>>(feat2, attn_l, attn_r, el, er);
  k_gat<<<gW, 256, 0, stream>>>(row_start, deg, csr_src, el, er, feat2, resval2,
                                gat_bias, conv_w, conv_b, nrm, h0, hsA);

  // resval2 dead now; res2 (f32) reuses its space
  k_gemm_nt_bias_relu<<<gM, 256, 0, stream>>>(node_feats, W_res, b_res, res2);

  k_gather_mid<<<gW, 256, 0, stream>>>(row_start, deg, csr_src, hsA, nrm, h0, hsB);
  k_gather_mid<<<gW, 256, 0, stream>>>(row_start, deg, csr_src, hsB, nrm, h0, hsA);
  k_gather_mid<<<gW, 256, 0, stream>>>(row_start, deg, csr_src, hsA, nrm, h0, hsB);
  k_gather_mid<<<gW, 256, 0, stream>>>(row_start, deg, csr_src, hsB, nrm, h0, hsA);
  k_gather_last<<<gW, 256, 0, stream>>>(row_start, deg, csr_src, hsA, nrm, h0, hout);

  k_finred<<<gM, 256, 0, stream>>>(hout, res2, hfin, bn);
  k_bnstats<<<1, 64, 0, stream>>>(bn, gamma, beta, bn + 128);
  k_bnapply<<<gV, 256, 0, stream>>>(hfin, bn + 128, out);
}

// Round 7
// 843.170 us; speedup vs baseline: 1.5299x; 1.0767x over previous
//
#include <hip/hip_runtime.h>
#include <math.h>

#define NN 100000
#define NE 1600000
#define NEG_SLOPE 0.2f

typedef __attribute__((ext_vector_type(8))) short bf16x8;
typedef __attribute__((ext_vector_type(4))) float f32x4;
typedef __attribute__((ext_vector_type(2))) float f32x2;

__device__ __forceinline__ float b2f(unsigned short u) {
  union { unsigned u; float f; } c; c.u = ((unsigned)u) << 16; return c.f;
}
__device__ __forceinline__ unsigned short f2b(float x) {
  union { float f; unsigned u; } c; c.f = x;
  unsigned r = c.u + 0x7FFFu + ((c.u >> 16) & 1u);
  return (unsigned short)(r >> 16);
}
__device__ __forceinline__ float readlane_f(float v, int l) {
  return __uint_as_float((unsigned)__builtin_amdgcn_readlane((int)__float_as_uint(v), l));
}
__device__ __forceinline__ void fma4(float4& acc, float s, const float4& b) {
  acc.x = fmaf(s, b.x, acc.x);
  acc.y = fmaf(s, b.y, acc.y);
  acc.z = fmaf(s, b.z, acc.z);
  acc.w = fmaf(s, b.w, acc.w);
}
__device__ __forceinline__ float wred(float v) {
#pragma unroll
  for (int off = 32; off > 0; off >>= 1) v += __shfl_xor(v, off, 64);
  return v;
}

// ---------------- utility ----------------
__global__ __launch_bounds__(256) void k_zero(int* __restrict__ p, int nwords) {
  int i = blockIdx.x * 256 + threadIdx.x;
  if (i < nwords) p[i] = 0;
}

// zero the dummy rows (index NN) of the bf16 ping-pong buffers
__global__ void k_zrow(unsigned short* __restrict__ a, unsigned short* __restrict__ b) {
  int i = threadIdx.x;
  a[(size_t)NN * 64 + i] = 0;
  b[(size_t)NN * 64 + i] = 0;
}

__global__ __launch_bounds__(256) void k_cast(const float* __restrict__ A, unsigned short* __restrict__ Ab) {
  int i = blockIdx.x * 256 + threadIdx.x;
  int i4 = i * 4;
  if (i4 < NN * 128) {
    float4 v = *(const float4*)&A[i4];
    ushort4 o; o.x = f2b(v.x); o.y = f2b(v.y); o.z = f2b(v.z); o.w = f2b(v.w);
    *(ushort4*)&Ab[i4] = o;
  }
}

// ---------------- CSR build (unordered within row) ----------------
__global__ __launch_bounds__(256) void k_deg(const int* __restrict__ dst, int* __restrict__ deg) {
  int i = blockIdx.x * 256 + threadIdx.x;
  if (i < NE) atomicAdd(&deg[dst[i]], 1);
}

__global__ __launch_bounds__(256) void k_alloc(const int* __restrict__ deg, int* __restrict__ row_start,
                                               int* __restrict__ counter, float* __restrict__ nrm) {
  int i = blockIdx.x * 256 + threadIdx.x;
  if (i < NN) {
    row_start[i] = atomicAdd(counter, deg[i]);
    nrm[i] = rsqrtf(fmaxf((float)deg[i], 1.0f));
  }
}

__global__ __launch_bounds__(256) void k_scatter(const int* __restrict__ src, const int* __restrict__ dst,
                                                 const int* __restrict__ row_start, int* __restrict__ cursor,
                                                 int* __restrict__ csr_src) {
  int i = blockIdx.x * 256 + threadIdx.x;
  if (i < NE) {
    int n = dst[i];
    int p = atomicAdd(&cursor[n], 1);
    csr_src[row_start[n] + p] = src[i];
  }
}

// ---------------- fold attention vectors into W_fc: w[p][k], p = side*4+h ----------------
__global__ __launch_bounds__(256) void k_prepw(const float* __restrict__ W_fc, const float* __restrict__ al,
                                               const float* __restrict__ ar, float* __restrict__ w) {
  int o = blockIdx.x * 256 + threadIdx.x;  // [0,1024)
  if (o >= 1024) return;
  int side = o >> 9;
  int h = (o >> 7) & 3;
  int k = o & 127;
  const float* a = side ? ar : al;
  float s = 0.f;
  for (int d = 0; d < 64; ++d) s += W_fc[k * 256 + h * 64 + d] * a[h * 64 + d];
  w[(side * 4 + h) * 128 + k] = s;
}

// ---------------- exact el/er GEMV: thread = (node, p) ----------------
__global__ __launch_bounds__(256) void k_elr2(const float* __restrict__ X, const float* __restrict__ w,
                                              float* __restrict__ el, float* __restrict__ er) {
  int n = blockIdx.x * 32 + (threadIdx.x >> 3);
  int p = threadIdx.x & 7;
  if (n >= NN) return;
  const float4* xr = (const float4*)(X + (size_t)n * 128);
  const float4* wr = (const float4*)(w + p * 128);
  float s = 0.f;
#pragma unroll
  for (int i = 0; i < 32; ++i) {
    float4 x = xr[i], ww = wr[i];
    s += x.x * ww.x + x.y * ww.y + x.z * ww.z + x.w * ww.w;
  }
  if (p < 4) el[n * 4 + p] = s;
  else er[n * 4 + (p - 4)] = s;
}

// ---------------- pre-pack B (both weight mats) into MFMA fragment order ----------------
__global__ __launch_bounds__(256) void k_prepB(const float* __restrict__ W_fc, const float* __restrict__ W_rg,
                                               unsigned short* __restrict__ Bp) {
  int y = blockIdx.y;
  const float* Bsrc = (y >> 1) ? W_rg : W_fc;
  int colbase = (y & 1) * 128;
  for (int e = blockIdx.x * 256 + threadIdx.x; e < 16384; e += 2048) {
    int n = e & 127, k = e >> 7;
    int p = colbase + n;
    int d = p >> 2, hh = p & 3;
    float v = Bsrc[k * 256 + hh * 64 + d];
    int nt = n >> 4, nn = n & 15, kt = k >> 5, quad = (k >> 3) & 3, j = k & 7;
    Bp[(size_t)y * 16384 + ((nt * 4 + kt) * 64 + quad * 16 + nn) * 8 + j] = f2b(v);
  }
}

// ---------------- merged bf16 MFMA GEMM ----------------
// y=0,1 -> feat8 (fp8, (n,d,h) interleaved); y=2,3 -> resval2 (bf16 interleaved)
__global__ __launch_bounds__(256) void k_gemm_mfma(const unsigned short* __restrict__ Abf,
                                                   const unsigned short* __restrict__ Bp,
                                                   unsigned* __restrict__ feat8u,
                                                   unsigned short* __restrict__ resval2) {
  __shared__ unsigned short Bl[16384];
  int tid = threadIdx.x;
  int half = blockIdx.y >> 1;
  int colbase = (blockIdx.y & 1) * 128;
  {
    const uint4* src = (const uint4*)(Bp + (size_t)blockIdx.y * 16384);
    uint4* dst4 = (uint4*)Bl;
#pragma unroll
    for (int i = 0; i < 8; ++i) dst4[tid + i * 256] = src[tid + i * 256];
  }
  __syncthreads();
  int w = tid >> 6, lane = tid & 63;
  int quad = lane >> 4;
  int row0 = blockIdx.x * 128;
  int mrow = row0 + (lane & 15);
  f32x4 acc[8][2];
#pragma unroll
  for (int rt = 0; rt < 8; ++rt)
#pragma unroll
    for (int c = 0; c < 2; ++c) acc[rt][c] = (f32x4){0.f, 0.f, 0.f, 0.f};
#pragma unroll
  for (int kt = 0; kt < 4; ++kt) {
    bf16x8 b0 = *(const bf16x8*)&Bl[(((w * 2 + 0) * 4 + kt) * 64 + lane) * 8];
    bf16x8 b1 = *(const bf16x8*)&Bl[(((w * 2 + 1) * 4 + kt) * 64 + lane) * 8];
    int kb = kt * 32 + quad * 8;
#pragma unroll
    for (int rt = 0; rt < 8; ++rt) {
      int rr = mrow + rt * 16; if (rr > NN - 1) rr = NN - 1;
      bf16x8 a = *(const bf16x8*)&Abf[(size_t)rr * 128 + kb];
      acc[rt][0] = __builtin_amdgcn_mfma_f32_16x16x32_bf16(b0, a, acc[rt][0], 0, 0, 0);
      acc[rt][1] = __builtin_amdgcn_mfma_f32_16x16x32_bf16(b1, a, acc[rt][1], 0, 0, 0);
    }
  }
#pragma unroll
  for (int rt = 0; rt < 8; ++rt) {
    int m = row0 + rt * 16 + (lane & 15);
    if (m < NN) {
#pragma unroll
      for (int c = 0; c < 2; ++c) {
        int col = colbase + (w * 2 + c) * 16 + quad * 4;
        if (half == 0) {
          int pk = __builtin_amdgcn_cvt_pk_fp8_f32(acc[rt][c][0], acc[rt][c][1], 0, false);
          pk = __builtin_amdgcn_cvt_pk_fp8_f32(acc[rt][c][2], acc[rt][c][3], pk, true);
          feat8u[(size_t)m * 64 + (col >> 2)] = (unsigned)pk;
        } else {
          ushort4 o;
          o.x = f2b(acc[rt][c][0]); o.y = f2b(acc[rt][c][1]);
          o.z = f2b(acc[rt][c][2]); o.w = f2b(acc[rt][c][3]);
          *(ushort4*)&resval2[(size_t)m * 256 + col] = o;
        }
      }
    }
  }
}

// ---------------- res2_f32[N x 64] = relu(A[N x 128] * W_res^T + b_res) (fp32 VALU) ----------------
__global__ __launch_bounds__(256) void k_gemm_nt_bias_relu(const float* __restrict__ A, const float* __restrict__ B,
                                                           const float* __restrict__ bias, float* __restrict__ C) {
  __shared__ float Bl[128][68];
  for (int idx = threadIdx.x; idx < 64 * 128; idx += 256) {
    int d = idx >> 7, k = idx & 127;
    Bl[k][d] = B[d * 128 + k];
  }
  __syncthreads();
  int tx = threadIdx.x & 15, ty = threadIdx.x >> 4;
  int row0 = blockIdx.x * 64 + ty * 4;
  const float* ap[4];
#pragma unroll
  for (int r = 0; r < 4; ++r) ap[r] = A + (size_t)min(row0 + r, NN - 1) * 128;
  float4 acc[4];
#pragma unroll
  for (int r = 0; r < 4; ++r) acc[r] = make_float4(0.f, 0.f, 0.f, 0.f);
#pragma unroll 2
  for (int k0 = 0; k0 < 128; k0 += 4) {
    float4 b0 = *(const float4*)&Bl[k0][tx * 4];
    float4 b1 = *(const float4*)&Bl[k0 + 1][tx * 4];
    float4 b2 = *(const float4*)&Bl[k0 + 2][tx * 4];
    float4 b3 = *(const float4*)&Bl[k0 + 3][tx * 4];
#pragma unroll
    for (int r = 0; r < 4; ++r) {
      float4 a = *(const float4*)(ap[r] + k0);
      fma4(acc[r], a.x, b0); fma4(acc[r], a.y, b1);
      fma4(acc[r], a.z, b2); fma4(acc[r], a.w, b3);
    }
  }
  float4 bv = *(const float4*)&bias[tx * 4];
#pragma unroll
  for (int r = 0; r < 4; ++r) {
    int row = row0 + r;
    if (row < NN) {
      float4 v;
      v.x = fmaxf(acc[r].x + bv.x, 0.f);
      v.y = fmaxf(acc[r].y + bv.y, 0.f);
      v.z = fmaxf(acc[r].z + bv.z, 0.f);
      v.w = fmaxf(acc[r].w + bv.w, 0.f);
      *(float4*)&C[(size_t)row * 64 + tx * 4] = v;
    }
  }
}

// ---------------- fused edge-softmax + aggregation + relu + head-mix conv ----------------
__global__ __launch_bounds__(256) void k_gat(const int* __restrict__ row_start, const int* __restrict__ deg,
                                             const int* __restrict__ csr_src, const float* __restrict__ el,
                                             const float* __restrict__ er, const unsigned* __restrict__ feat8u,
                                             const unsigned short* __restrict__ resval2,
                                             const float* __restrict__ gat_bias, const float* __restrict__ conv_w,
                                             const float* __restrict__ conv_b, const float* __restrict__ nrm,
                                             float* __restrict__ h0, unsigned short* __restrict__ hsA) {
  int n = blockIdx.x * 4 + (threadIdx.x >> 6);
  int lane = threadIdx.x & 63;
  if (n >= NN) return;
  int s0 = row_start[n], cnt = deg[n];
  float4 er4 = *(const float4*)&er[n * 4];
  f32x2 acc01 = (f32x2){0.f, 0.f}, acc23 = (f32x2){0.f, 0.f};
  float den0 = 0.f, den1 = 0.f, den2 = 0.f, den3 = 0.f;
  for (int base = 0; base < cnt; base += 64) {
    int j = base + lane;
    int s = 0;
    float x0 = 0.f, x1 = 0.f, x2 = 0.f, x3 = 0.f;
    if (j < cnt) {
      s = csr_src[s0 + j];
      float4 el4 = *(const float4*)&el[s * 4];
      float e0 = el4.x + er4.x; e0 = (e0 > 0.f) ? e0 : NEG_SLOPE * e0;
      float e1 = el4.y + er4.y; e1 = (e1 > 0.f) ? e1 : NEG_SLOPE * e1;
      float e2 = el4.z + er4.z; e2 = (e2 > 0.f) ? e2 : NEG_SLOPE * e2;
      float e3 = el4.w + er4.w; e3 = (e3 > 0.f) ? e3 : NEG_SLOPE * e3;
      x0 = __expf(e0); x1 = __expf(e1); x2 = __expf(e2); x3 = __expf(e3);
      den0 += x0; den1 += x1; den2 += x2; den3 += x3;
    }
    int m = cnt - base; if (m > 64) m = 64;
    int mr = (m + 3) & ~3;
    for (int t = 0; t < mr; t += 4) {
      int ss0 = __builtin_amdgcn_readlane(s, t);
      int ss1 = __builtin_amdgcn_readlane(s, t + 1);
      int ss2 = __builtin_amdgcn_readlane(s, t + 2);
      int ss3 = __builtin_amdgcn_readlane(s, t + 3);
      unsigned f0 = feat8u[(size_t)ss0 * 64 + lane];
      unsigned f1 = feat8u[(size_t)ss1 * 64 + lane];
      unsigned f2 = feat8u[(size_t)ss2 * 64 + lane];
      unsigned f3 = feat8u[(size_t)ss3 * 64 + lane];
      {
        f32x2 a01 = (f32x2){readlane_f(x0, t), readlane_f(x1, t)};
        f32x2 a23 = (f32x2){readlane_f(x2, t), readlane_f(x3, t)};
        f32x2 lo = __builtin_amdgcn_cvt_pk_f32_fp8((int)f0, false);
        f32x2 hi = __builtin_amdgcn_cvt_pk_f32_fp8((int)f0, true);
        acc01 += a01 * lo; acc23 += a23 * hi;
      }
      {
        f32x2 a01 = (f32x2){readlane_f(x0, t + 1), readlane_f(x1, t + 1)};
        f32x2 a23 = (f32x2){readlane_f(x2, t + 1), readlane_f(x3, t + 1)};
        f32x2 lo = __builtin_amdgcn_cvt_pk_f32_fp8((int)f1, false);
        f32x2 hi = __builtin_amdgcn_cvt_pk_f32_fp8((int)f1, true);
        acc01 += a01 * lo; acc23 += a23 * hi;
      }
      {
        f32x2 a01 = (f32x2){readlane_f(x0, t + 2), readlane_f(x1, t + 2)};
        f32x2 a23 = (f32x2){readlane_f(x2, t + 2), readlane_f(x3, t + 2)};
        f32x2 lo = __builtin_amdgcn_cvt_pk_f32_fp8((int)f2, false);
        f32x2 hi = __builtin_amdgcn_cvt_pk_f32_fp8((int)f2, true);
        acc01 += a01 * lo; acc23 += a23 * hi;
      }
      {
        f32x2 a01 = (f32x2){readlane_f(x0, t + 3), readlane_f(x1, t + 3)};
        f32x2 a23 = (f32x2){readlane_f(x2, t + 3), readlane_f(x3, t + 3)};
        f32x2 lo = __builtin_amdgcn_cvt_pk_f32_fp8((int)f3, false);
        f32x2 hi = __builtin_amdgcn_cvt_pk_f32_fp8((int)f3, true);
        acc01 += a01 * lo; acc23 += a23 * hi;
      }
    }
  }
  den0 = wred(den0); den1 = wred(den1); den2 = wred(den2); den3 = wred(den3);
  float i0 = 1.f / fmaxf(den0, 1e-9f);
  float i1 = 1.f / fmaxf(den1, 1e-9f);
  float i2 = 1.f / fmaxf(den2, 1e-9f);
  float i3 = 1.f / fmaxf(den3, 1e-9f);
  ushort4 rv = *(const ushort4*)&resval2[(size_t)n * 256 + lane * 4];
  float hmix = conv_b[0];
  float t0;
  t0 = fmaf(acc01.x, i0, b2f(rv.x) + gat_bias[lane]);       t0 = fmaxf(t0, 0.f); hmix = fmaf(conv_w[0], t0, hmix);
  t0 = fmaf(acc01.y, i1, b2f(rv.y) + gat_bias[64 + lane]);  t0 = fmaxf(t0, 0.f); hmix = fmaf(conv_w[1], t0, hmix);
  t0 = fmaf(acc23.x, i2, b2f(rv.z) + gat_bias[128 + lane]); t0 = fmaxf(t0, 0.f); hmix = fmaf(conv_w[2], t0, hmix);
  t0 = fmaf(acc23.y, i3, b2f(rv.w) + gat_bias[192 + lane]); t0 = fmaxf(t0, 0.f); hmix = fmaf(conv_w[3], t0, hmix);
  size_t o = (size_t)n * 64 + lane;
  h0[o] = hmix;
  hsA[o] = f2b(hmix * nrm[n]);
}

// ---------------- APPNP step (mid): hs_out = bf16(nrm[n]*(0.5*nrm[n]*sum hs_in[src] + 0.5*h0)) ----------------
__global__ __launch_bounds__(256) void k_gather_mid(const int* __restrict__ row_start, const int* __restrict__ deg,
                                                    const int* __restrict__ csr_src,
                                                    const unsigned short* __restrict__ hs_in,
                                                    const float* __restrict__ nrm, const float* __restrict__ h0,
                                                    unsigned short* __restrict__ hs_out) {
  int n = blockIdx.x * 4 + (threadIdx.x >> 6);
  int lane = threadIdx.x & 63;
  if (n >= NN) return;
  int s0 = row_start[n], cnt = deg[n];
  float acc = 0.f;
  for (int base = 0; base < cnt; base += 64) {
    int j = base + lane;
    int s = (j < cnt) ? csr_src[s0 + j] : NN;
    int m = cnt - base; if (m > 64) m = 64;
    int mr = (m + 7) & ~7;
    for (int t = 0; t < mr; t += 8) {
      int ss0 = __builtin_amdgcn_readlane(s, t);
      int ss1 = __builtin_amdgcn_readlane(s, t + 1);
      int ss2 = __builtin_amdgcn_readlane(s, t + 2);
      int ss3 = __builtin_amdgcn_readlane(s, t + 3);
      int ss4 = __builtin_amdgcn_readlane(s, t + 4);
      int ss5 = __builtin_amdgcn_readlane(s, t + 5);
      int ss6 = __builtin_amdgcn_readlane(s, t + 6);
      int ss7 = __builtin_amdgcn_readlane(s, t + 7);
      float u0 = b2f(hs_in[(size_t)ss0 * 64 + lane]);
      float u1 = b2f(hs_in[(size_t)ss1 * 64 + lane]);
      float u2 = b2f(hs_in[(size_t)ss2 * 64 + lane]);
      float u3 = b2f(hs_in[(size_t)ss3 * 64 + lane]);
      float u4 = b2f(hs_in[(size_t)ss4 * 64 + lane]);
      float u5 = b2f(hs_in[(size_t)ss5 * 64 + lane]);
      float u6 = b2f(hs_in[(size_t)ss6 * 64 + lane]);
      float u7 = b2f(hs_in[(size_t)ss7 * 64 + lane]);
      acc += ((u0 + u1) + (u2 + u3)) + ((u4 + u5) + (u6 + u7));
    }
  }
  size_t o = (size_t)n * 64 + lane;
  float nn_ = nrm[n];
  float v = fmaf(0.5f * nn_, acc, 0.5f * h0[o]);
  hs_out[o] = f2b(v * nn_);
}

// ---------------- APPNP step (last): hout = bf16(0.5*nrm[n]*sum hs_in[src] + 0.5*h0) ----------------
__global__ __launch_bounds__(256) void k_gather_last(const int* __restrict__ row_start, const int* __restrict__ deg,
                                                     const int* __restrict__ csr_src,
                                                     const unsigned short* __restrict__ hs_in,
                                                     const float* __restrict__ nrm, const float* __restrict__ h0,
                                                     unsigned short* __restrict__ hout) {
  int n = blockIdx.x * 4 + (threadIdx.x >> 6);
  int lane = threadIdx.x & 63;
  if (n >= NN) return;
  int s0 = row_start[n], cnt = deg[n];
  float acc = 0.f;
  for (int base = 0; base < cnt; base += 64) {
    int j = base + lane;
    int s = (j < cnt) ? csr_src[s0 + j] : NN;
    int m = cnt - base; if (m > 64) m = 64;
    int mr = (m + 7) & ~7;
    for (int t = 0; t < mr; t += 8) {
      int ss0 = __builtin_amdgcn_readlane(s, t);
      int ss1 = __builtin_amdgcn_readlane(s, t + 1);
      int ss2 = __builtin_amdgcn_readlane(s, t + 2);
      int ss3 = __builtin_amdgcn_readlane(s, t + 3);
      int ss4 = __builtin_amdgcn_readlane(s, t + 4);
      int ss5 = __builtin_amdgcn_readlane(s, t + 5);
      int ss6 = __builtin_amdgcn_readlane(s, t + 6);
      int ss7 = __builtin_amdgcn_readlane(s, t + 7);
      float u0 = b2f(hs_in[(size_t)ss0 * 64 + lane]);
      float u1 = b2f(hs_in[(size_t)ss1 * 64 + lane]);
      float u2 = b2f(hs_in[(size_t)ss2 * 64 + lane]);
      float u3 = b2f(hs_in[(size_t)ss3 * 64 + lane]);
      float u4 = b2f(hs_in[(size_t)ss4 * 64 + lane]);
      float u5 = b2f(hs_in[(size_t)ss5 * 64 + lane]);
      float u6 = b2f(hs_in[(size_t)ss6 * 64 + lane]);
      float u7 = b2f(hs_in[(size_t)ss7 * 64 + lane]);
      acc += ((u0 + u1) + (u2 + u3)) + ((u4 + u5) + (u6 + u7));
    }
  }
  size_t o = (size_t)n * 64 + lane;
  float v = fmaf(0.5f * nrm[n], acc, 0.5f * h0[o]);
  hout[o] = f2b(v);
}

// ---------------- final residual add + BN partial sums ----------------
__global__ __launch_bounds__(256) void k_finred(const unsigned short* __restrict__ hl,
                                                const float* __restrict__ res2, float* __restrict__ hfin,
                                                float* __restrict__ bn) {
  __shared__ float s1[256], s2[256];
  int d = threadIdx.x & 63;
  int rb = blockIdx.x * 64;
  float sum = 0.f, sq = 0.f;
  for (int r = threadIdx.x >> 6; r < 64; r += 4) {
    int n = rb + r;
    if (n < NN) {
      size_t idx = (size_t)n * 64 + d;
      float v = b2f(hl[idx]) + res2[idx];
      hfin[idx] = v;
      sum += v; sq += v * v;
    }
  }
  s1[threadIdx.x] = sum; s2[threadIdx.x] = sq;
  __syncthreads();
  if (threadIdx.x < 128) { s1[threadIdx.x] += s1[threadIdx.x + 128]; s2[threadIdx.x] += s2[threadIdx.x + 128]; }
  __syncthreads();
  if (threadIdx.x < 64) {
    atomicAdd(&bn[d], s1[threadIdx.x] + s1[threadIdx.x + 64]);
    atomicAdd(&bn[64 + d], s2[threadIdx.x] + s2[threadIdx.x + 64]);
  }
}

__global__ void k_bnstats(const float* __restrict__ bn, const float* __restrict__ gamma,
                          const float* __restrict__ beta, float* __restrict__ bns) {
  int d = threadIdx.x;
  float mu = bn[d] * (1.0f / NN);
  float var = fmaxf(bn[64 + d] * (1.0f / NN) - mu * mu, 0.f);
  float sc = rsqrtf(var + 1e-5f) * gamma[d];
  bns[d] = sc;
  bns[64 + d] = beta[d] - mu * sc;
}

__global__ __launch_bounds__(256) void k_bnapply(const float* __restrict__ h, const float* __restrict__ bns,
                                                 float* __restrict__ out) {
  int i = blockIdx.x * 256 + threadIdx.x;
  if (i < NN * 64) {
    int d = i & 63;
    out[i] = fmaf(h[i], bns[d], bns[64 + d]);
  }
}

extern "C" void kernel_launch(void* const* d_in, const int* in_sizes, int n_in,
                              void* d_out, int out_size, void* d_ws, size_t ws_size,
                              hipStream_t stream) {
  const float* node_feats = (const float*)d_in[0];
  const int* src = (const int*)d_in[1];
  const int* dst = (const int*)d_in[2];
  const float* W_fc = (const float*)d_in[3];
  const float* attn_l = (const float*)d_in[4];
  const float* attn_r = (const float*)d_in[5];
  const float* W_res_gat = (const float*)d_in[6];
  const float* gat_bias = (const float*)d_in[7];
  const float* conv_w = (const float*)d_in[8];
  const float* conv_b = (const float*)d_in[9];
  const float* W_res = (const float*)d_in[10];
  const float* b_res = (const float*)d_in[11];
  const float* gamma = (const float*)d_in[12];
  const float* beta = (const float*)d_in[13];
  float* out = (float*)d_out;

  char* base = (char*)d_ws;
  size_t off = 0;
  auto alloc = [&](size_t bytes) -> char* {
    char* p = base + off;
    off = (off + bytes + 255) & ~(size_t)255;
    return p;
  };
  unsigned* feat8u        = (unsigned*)alloc((size_t)NN * 256);                  // 25.6 MB fp8 (n,d,h)
  unsigned short* resval2 = (unsigned short*)alloc((size_t)NN * 256 * 2);        // 51.2 MB bf16; res2 f32 aliases after k_gat
  float* res2             = (float*)resval2;
  float* el               = (float*)alloc((size_t)NN * 4 * 4);
  float* er               = (float*)alloc((size_t)NN * 4 * 4);
  float* h0               = (float*)alloc((size_t)NN * 64 * 4);                  // 25.6 MB; Abf aliases BEFORE k_gat; hfin at end
  unsigned short* Abf     = (unsigned short*)h0;
  unsigned short* hsA     = (unsigned short*)alloc((size_t)(NN + 1) * 64 * 2);   // 12.8 MB bf16 + dummy row
  unsigned short* hsB     = (unsigned short*)alloc((size_t)(NN + 1) * 64 * 2);
  unsigned short* hout    = (unsigned short*)alloc((size_t)NN * 64 * 2);         // 12.8 MB bf16
  int* csr_src            = (int*)alloc((size_t)NE * 4);
  float* nrm              = (float*)alloc((size_t)NN * 4);
  int* row_start          = (int*)alloc((size_t)NN * 4);
  unsigned short* Bpacked = (unsigned short*)alloc((size_t)4 * 16384 * 2);
  float* w_elr            = (float*)alloc((size_t)8 * 128 * 4);
  size_t zoff = off;
  int* deg                = (int*)alloc((size_t)NN * 4);
  int* cursor             = (int*)alloc((size_t)NN * 4);
  int* counter            = (int*)alloc(256);
  float* bn               = (float*)alloc(256 * 4);
  float* hfin             = h0;

  int zwords = (int)((off - zoff) / 4);
  int gE = (NE + 255) / 256;
  int gN = (NN + 255) / 256;
  int gW = (NN + 3) / 4;
  int gM = (NN + 63) / 64;
  int gV = (NN * 64 + 255) / 256;

  k_zero<<<(zwords + 255) / 256, 256, 0, stream>>>((int*)(base + zoff), zwords);
  k_zrow<<<1, 64, 0, stream>>>(hsA, hsB);
  k_deg<<<gE, 256, 0, stream>>>(dst, deg);
  k_alloc<<<gN, 256, 0, stream>>>(deg, row_start, counter, nrm);
  k_scatter<<<gE, 256, 0, stream>>>(src, dst, row_start, cursor, csr_src);

  k_cast<<<(NN * 128 / 4 + 255) / 256, 256, 0, stream>>>(node_feats, Abf);
  k_prepB<<<dim3(8, 4), 256, 0, stream>>>(W_fc, W_res_gat, Bpacked);
  k_prepw<<<4, 256, 0, stream>>>(W_fc, attn_l, attn_r, w_elr);
  k_gemm_mfma<<<dim3((NN + 127) / 128, 4), 256, 0, stream>>>(Abf, Bpacked, feat8u, resval2);

  k_elr2<<<(NN + 31) / 32, 256, 0, stream>>>(node_feats, w_elr, el, er);
  k_gat<<<gW, 256, 0, stream>>>(row_start, deg, csr_src, el, er, feat8u, resval2,
                                gat_bias, conv_w, conv_b, nrm, h0, hsA);

  // resval2 dead now; res2 (f32) reuses its space
  k_gemm_nt_bias_relu<<<gM, 256, 0, stream>>>(node_feats, W_res, b_res, res2);

  k_gather_mid<<<gW, 256, 0, stream>>>(row_start, deg, csr_src, hsA, nrm, h0, hsB);
  k_gather_mid<<<gW, 256, 0, stream>>>(row_start, deg, csr_src, hsB, nrm, h0, hsA);
  k_gather_mid<<<gW, 256, 0, stream>>>(row_start, deg, csr_src, hsA, nrm, h0, hsB);
  k_gather_mid<<<gW, 256, 0, stream>>>(row_start, deg, csr_src, hsB, nrm, h0, hsA);
  k_gather_last<<<gW, 256, 0, stream>>>(row_start, deg, csr_src, hsA, nrm, h0, hout);

  k_finred<<<gM, 256, 0, stream>>>(hout, res2, hfin, bn);
  k_bnstats<<<1, 64, 0, stream>>>(bn, gamma, beta, bn + 128);
  k_bnapply<<<gV, 256, 0, stream>>>(hfin, bn + 128, out);
}